// Round 6
// baseline (605.105 us; speedup 1.0000x reference)
//
#include <hip/hip_runtime.h>
#include <hip/hip_bf16.h>

typedef __bf16 bf16x8 __attribute__((ext_vector_type(8)));
typedef __bf16 bf16x4 __attribute__((ext_vector_type(4)));
typedef float  f32x4  __attribute__((ext_vector_type(4)));
typedef float  f32x16 __attribute__((ext_vector_type(16)));

#define NPOS 49
#define NHEADS 8
#define SCALE_F 0.17677669529663687f

// ---- legacy (round-5) LDS layout ----
#define SLICE_B   16896
#define QK_ROW_B  264
#define VS_OFF    8192
#define VS_ROW_B  136
#define XWT_PITCH 264
#define AOT_PITCH 264
#define BIAS_OFF  67584
#define BO_OFF    77188
#define LDS_BYTES 78212

// ---- new qkv kernel ----
#define XW2_PITCH 268                    // elements; 536 B rows -> 2-way-max LDS banking
#define QKV_LDS   (64 * XW2_PITCH * 2)   // 34304 B
#define ATT_LDS   (4 * 8192)             // 32768 B (4 P-buffers)

static __device__ __forceinline__ f32x16 zero16() {
  f32x16 z;
#pragma unroll
  for (int i = 0; i < 16; ++i) z[i] = 0.f;
  return z;
}

__global__ void prep_kernel(const float* __restrict__ Wq, const float* __restrict__ Wkv,
                            const float* __restrict__ Wo, const float* __restrict__ pos,
                            const int* __restrict__ rel, __bf16* __restrict__ wqkv,
                            __bf16* __restrict__ wo, float* __restrict__ bias) {
  int idx = blockIdx.x * 256 + threadIdx.x;
  if (idx < 256 * 256) wqkv[idx] = (__bf16)Wq[idx];              // q rows 0..255
  if (idx < 512 * 256) wqkv[256 * 256 + idx] = (__bf16)Wkv[idx]; // k 256..511, v 512..767
  if (idx < 256 * 256) wo[idx] = (__bf16)Wo[idx];
  if (idx < 49 * 49) bias[idx] = pos[rel[idx * 2] * 13 + rel[idx * 2 + 1]];
}

// =====================================================================
// NEW PATH kernel 1: qkv projection. One block per window, 4 waves.
// Each wave computes 6 strips (3 pairs) of 32 output rows; outputs go to
// global q[win][h][49][32], k same, vT[win][h][32][64] (bf16).
// =====================================================================
__global__ __launch_bounds__(256, 4) void qkv_kernel(
    const float* __restrict__ x, const __bf16* __restrict__ wqkv,
    __bf16* __restrict__ qg, __bf16* __restrict__ kg, __bf16* __restrict__ vtg) {
  extern __shared__ char smem[];
  __bf16* xwT = (__bf16*)smem;

  const int tid = threadIdx.x;
  const int bid = blockIdx.x;
  const int work = (bid & 7) * 512 + (bid >> 3);  // XCD swizzle
  const int b  = work >> 8;
  const int i1 = (work >> 4) & 15;
  const int i2 = work & 15;
  const int r0 = i1 * 7, c0 = i2 * 7;
  const int wave = tid >> 6, lane = tid & 63;
  const int l31 = lane & 31, g2 = lane >> 5;

  // stage x window -> xwT [64 pos][268 ch] bf16 (zero-padded pos>=49)
  {
    const int n = tid & 63, cb = tid >> 6;
    const int np = (n < NPOS) ? n : 0;
    const float zf = (n < NPOS) ? 1.f : 0.f;
    const int pr = np / 7, pc = np - pr * 7;
    const float* xg = x + (size_t)b * 256 * 12544 + (size_t)(r0 + pr) * 112 + (c0 + pc);
    float tmp[64];
#pragma unroll
    for (int it = 0; it < 64; ++it)
      tmp[it] = xg[(size_t)(it * 4 + cb) * 12544];
#pragma unroll
    for (int it = 0; it < 64; ++it)
      xwT[n * XW2_PITCH + it * 4 + cb] = (__bf16)(tmp[it] * zf);
  }
  __syncthreads();

  const size_t hb = (size_t)work * 8;

#pragma unroll 1
  for (int p = 3 * wave; p < 3 * wave + 3; ++p) {
    const __bf16* Ap0 = wqkv + (size_t)(64 * p + l31) * 256 + g2 * 8;
    const __bf16* Ap1 = Ap0 + 32 * 256;
    const __bf16* Bp  = xwT + l31 * XW2_PITCH + g2 * 8;
    f32x16 a00 = zero16(), a01 = zero16(), a10 = zero16(), a11 = zero16();
    __builtin_amdgcn_s_setprio(1);
#pragma unroll
    for (int ks = 0; ks < 16; ++ks) {
      bf16x8 B0 = *(const bf16x8*)(Bp + ks * 16);
      bf16x8 B1 = *(const bf16x8*)(Bp + 32 * XW2_PITCH + ks * 16);
      bf16x8 A0 = *(const bf16x8*)(Ap0 + ks * 16);
      bf16x8 A1 = *(const bf16x8*)(Ap1 + ks * 16);
      a00 = __builtin_amdgcn_mfma_f32_32x32x16_bf16(A0, B0, a00, 0, 0, 0);
      a01 = __builtin_amdgcn_mfma_f32_32x32x16_bf16(A0, B1, a01, 0, 0, 0);
      a10 = __builtin_amdgcn_mfma_f32_32x32x16_bf16(A1, B0, a10, 0, 0, 0);
      a11 = __builtin_amdgcn_mfma_f32_32x32x16_bf16(A1, B1, a11, 0, 0, 0);
    }
    __builtin_amdgcn_s_setprio(0);
#define QKV_STORE(ACC, S, NT)                                                  \
    {                                                                          \
      const int sec = (S) >> 3, h = (S) & 7;                                   \
      const int n_ = (NT) * 32 + l31;                                          \
      if (sec < 2) {                                                           \
        if (n_ < NPOS) {                                                       \
          __bf16* bp = (sec ? kg : qg) + (hb + h) * 1568 + n_ * 32;            \
          _Pragma("unroll") for (int rb = 0; rb < 4; ++rb) {                   \
            bf16x4 v4;                                                         \
            v4[0] = (__bf16)ACC[rb * 4 + 0]; v4[1] = (__bf16)ACC[rb * 4 + 1];  \
            v4[2] = (__bf16)ACC[rb * 4 + 2]; v4[3] = (__bf16)ACC[rb * 4 + 3];  \
            *(bf16x4*)(bp + 8 * rb + 4 * g2) = v4;                             \
          }                                                                    \
        }                                                                      \
      } else {                                                                 \
        __bf16* vp = vtg + (hb + h) * 2048 + n_;                               \
        _Pragma("unroll") for (int rg = 0; rg < 16; ++rg) {                    \
          const int dd = (rg & 3) + 8 * (rg >> 2) + 4 * g2;                    \
          vp[dd * 64] = (__bf16)ACC[rg];                                       \
        }                                                                      \
      }                                                                        \
    }
    QKV_STORE(a00, 2 * p, 0)
    QKV_STORE(a01, 2 * p, 1)
    QKV_STORE(a10, 2 * p + 1, 0)
    QKV_STORE(a11, 2 * p + 1, 1)
  }
}

// =====================================================================
// NEW PATH kernel 2: attention. One wave per (window, head); 4 waves/block;
// no __syncthreads at all. P lives in an 8 KB per-wave LDS buffer.
// =====================================================================
__global__ __launch_bounds__(256, 3) void att_kernel(
    const __bf16* __restrict__ qg, const __bf16* __restrict__ kg,
    const __bf16* __restrict__ vtg, const float* __restrict__ bias_g,
    float* __restrict__ attng, __bf16* __restrict__ aoT_g) {
  extern __shared__ char smem[];
  const int tid = threadIdx.x;
  const int bid = blockIdx.x;
  const int work = (bid & 7) * 1024 + (bid >> 3);  // XCD swizzle, 8192 blocks
  const int win  = work >> 1;
  const int wave = tid >> 6, lane = tid & 63;
  const int head = (work & 1) * 4 + wave;
  const int c16 = lane & 15, g4 = lane >> 4;
  char* Pb = smem + wave * 8192;

  const size_t hidx = (size_t)win * 8 + head;
  const __bf16* qb = qg + hidx * 1568;
  const __bf16* kb = kg + hidx * 1568;
  const __bf16* vb = vtg + hidx * 2048;

  // fragments straight from global (row 48 clamped: rows 49..63 are dups of 48,
  // harmless: i>48 rows discarded, j>48 cols masked)
  bf16x8 qf[4], kf[4];
#pragma unroll
  for (int t = 0; t < 4; ++t) {
    int rr = t * 16 + c16; rr = rr > 48 ? 48 : rr;
    qf[t] = *(const bf16x8*)(qb + rr * 32 + g4 * 8);
    kf[t] = *(const bf16x8*)(kb + rr * 32 + g4 * 8);
  }
  bf16x8 vf[2][2];
#pragma unroll
  for (int nt = 0; nt < 2; ++nt)
#pragma unroll
    for (int ks = 0; ks < 2; ++ks)
      vf[nt][ks] = *(const bf16x8*)(vb + (nt * 16 + c16) * 64 + ks * 32 + g4 * 8);

  f32x4 dacc[4][4];
  const f32x4 z4 = {0.f, 0.f, 0.f, 0.f};
  __builtin_amdgcn_s_setprio(1);
#pragma unroll
  for (int mt = 0; mt < 4; ++mt)
#pragma unroll
    for (int nt = 0; nt < 4; ++nt)
      dacc[mt][nt] = __builtin_amdgcn_mfma_f32_16x16x32_bf16(qf[mt], kf[nt], z4, 0, 0, 0);
  __builtin_amdgcn_s_setprio(0);

  // softmax (no max-subtraction: scores are O(1); identical to reference math)
#pragma unroll
  for (int mt = 0; mt < 4; ++mt) {
#pragma unroll
    for (int r = 0; r < 4; ++r) {
      const int i = mt * 16 + g4 * 4 + r;
      float p[4], s = 0.f;
#pragma unroll
      for (int nt = 0; nt < 4; ++nt) {
        const int j = nt * 16 + c16;
        float val = dacc[mt][nt][r] * SCALE_F;
        if (j < NPOS) {
          if (i < NPOS) val += bias_g[i * 49 + j];
        } else {
          val = -1e30f;
        }
        p[nt] = __expf(val); s += p[nt];
      }
      s += __shfl_xor(s, 1); s += __shfl_xor(s, 2);
      s += __shfl_xor(s, 4); s += __shfl_xor(s, 8);
      const float inv = 1.f / s;
      if (i < NPOS) {
        float* ap = attng + ((size_t)(win * NHEADS + head) * 49 + i) * 49;
#pragma unroll
        for (int nt = 0; nt < 4; ++nt) {
          const int j = nt * 16 + c16;
          if (j < NPOS) ap[j] = p[nt] * inv;
        }
      }
#pragma unroll
      for (int nt = 0; nt < 4; ++nt) {
        const int j = nt * 16 + c16;
        *(__bf16*)(Pb + i * 128 + 16 * ((j >> 3) ^ (i & 7)) + 2 * (j & 7)) = (__bf16)(p[nt] * inv);
      }
    }
  }

  // PV
  f32x4 pacc[4][2];
  __builtin_amdgcn_s_setprio(1);
#pragma unroll
  for (int mt = 0; mt < 4; ++mt) {
    const int i = mt * 16 + c16;
    bf16x8 pa0 = *(const bf16x8*)(Pb + i * 128 + 16 * ((0 + g4) ^ (i & 7)));
    bf16x8 pa1 = *(const bf16x8*)(Pb + i * 128 + 16 * ((4 + g4) ^ (i & 7)));
#pragma unroll
    for (int nt = 0; nt < 2; ++nt) {
      f32x4 acc = {0.f, 0.f, 0.f, 0.f};
      acc = __builtin_amdgcn_mfma_f32_16x16x32_bf16(pa0, vf[nt][0], acc, 0, 0, 0);
      acc = __builtin_amdgcn_mfma_f32_16x16x32_bf16(pa1, vf[nt][1], acc, 0, 0, 0);
      pacc[mt][nt] = acc;
    }
  }
  __builtin_amdgcn_s_setprio(0);

  __bf16* ag = aoT_g + (size_t)win * 12544;
#pragma unroll
  for (int mt = 0; mt < 4; ++mt)
#pragma unroll
    for (int e = 0; e < 4; ++e) {
      const int pos = mt * 16 + g4 * 4 + e;
      if (pos < NPOS) {
        ag[pos * 256 + head * 32 + c16]      = (__bf16)pacc[mt][0][e];
        ag[pos * 256 + head * 32 + 16 + c16] = (__bf16)pacc[mt][1][e];
      }
    }
}

// =====================================================================
// LEGACY fallback path (round-5, proven): monolithic / split attn kernel
// =====================================================================
template <int MODE>
__global__ __launch_bounds__(256, 2) void attn_kernel(
    const float* __restrict__ x, const __bf16* __restrict__ wqkv,
    const __bf16* __restrict__ wo, const float* __restrict__ bias_g,
    const float* __restrict__ bo_g, float* __restrict__ outg,
    float* __restrict__ attng, __bf16* __restrict__ aoT_g) {
  extern __shared__ char smem[];
  __bf16* xwT = (__bf16*)smem;
  __bf16* aoT = (__bf16*)smem;
  float* bias_s = (float*)(smem + BIAS_OFF);
  float* bo_s   = (float*)(smem + BO_OFF);

  const int tid = threadIdx.x;
  const int bid = blockIdx.x;
  const int work = (bid & 7) * 512 + (bid >> 3);
  const int b  = work >> 8;
  const int i1 = (work >> 4) & 15;
  const int i2 = work & 15;
  const int r0 = i1 * 7, c0 = i2 * 7;
  const int wave = tid >> 6, lane = tid & 63;
  const int l31 = lane & 31, g2 = lane >> 5;
  const int c16 = lane & 15, g4 = lane >> 4;
  char* slice = smem + wave * SLICE_B;

  {
    const int n = tid & 63, cb = tid >> 6;
    const int np = (n < NPOS) ? n : 0;
    const float zf = (n < NPOS) ? 1.f : 0.f;
    const int pr = np / 7, pc = np - pr * 7;
    const float* xg = x + (size_t)b * 256 * 12544 + (size_t)(r0 + pr) * 112 + (c0 + pc);
    float tmp[64];
#pragma unroll
    for (int it = 0; it < 64; ++it)
      tmp[it] = xg[(size_t)(it * 4 + cb) * 12544];
#pragma unroll
    for (int it = 0; it < 64; ++it)
      xwT[n * XWT_PITCH + it * 4 + cb] = (__bf16)(tmp[it] * zf);
    const float4* bg4 = (const float4*)bias_g;
    for (int i = tid; i < 600; i += 256) ((float4*)bias_s)[i] = bg4[i];
    if (tid == 0) bias_s[2400] = bias_g[2400];
    if constexpr (MODE == 0) bo_s[tid] = bo_g[tid];
  }
  __syncthreads();

  bf16x8 Bf0[16], Bf1[16];
  {
    const __bf16* Bp = xwT + l31 * XWT_PITCH + g2 * 8;
#pragma unroll
    for (int ks = 0; ks < 16; ++ks) {
      Bf0[ks] = *(const bf16x8*)(Bp + ks * 16);
      Bf1[ks] = *(const bf16x8*)(Bp + 32 * XWT_PITCH + ks * 16);
    }
  }
  __syncthreads();

  char* vsb = slice + VS_OFF;
  {
    const __bf16* Ap0 = wqkv + (size_t)(512 + 64 * wave + l31) * 256 + g2 * 8;
    const __bf16* Ap1 = Ap0 + 32 * 256;
    f32x16 a00 = zero16(), a01 = zero16(), a10 = zero16(), a11 = zero16();
    __builtin_amdgcn_s_setprio(1);
#pragma unroll
    for (int ks = 0; ks < 16; ++ks) {
      bf16x8 A0 = *(const bf16x8*)(Ap0 + ks * 16);
      bf16x8 A1 = *(const bf16x8*)(Ap1 + ks * 16);
      a00 = __builtin_amdgcn_mfma_f32_32x32x16_bf16(A0, Bf0[ks], a00, 0, 0, 0);
      a01 = __builtin_amdgcn_mfma_f32_32x32x16_bf16(A0, Bf1[ks], a01, 0, 0, 0);
      a10 = __builtin_amdgcn_mfma_f32_32x32x16_bf16(A1, Bf0[ks], a10, 0, 0, 0);
      a11 = __builtin_amdgcn_mfma_f32_32x32x16_bf16(A1, Bf1[ks], a11, 0, 0, 0);
    }
    __builtin_amdgcn_s_setprio(0);
#pragma unroll
    for (int rg = 0; rg < 16; ++rg) {
      const int dd = (rg & 3) + 8 * (rg >> 2) + 4 * g2;
      *(__bf16*)(vsb + dd * VS_ROW_B + l31 * 2)              = (__bf16)a00[rg];
      *(__bf16*)(vsb + dd * VS_ROW_B + 64 + l31 * 2)         = (__bf16)a01[rg];
      *(__bf16*)(vsb + (32 + dd) * VS_ROW_B + l31 * 2)       = (__bf16)a10[rg];
      *(__bf16*)(vsb + (32 + dd) * VS_ROW_B + 64 + l31 * 2)  = (__bf16)a11[rg];
    }
  }
  bf16x8 vf[2][2][2];
#pragma unroll
  for (int hh = 0; hh < 2; ++hh)
#pragma unroll
    for (int nt = 0; nt < 2; ++nt)
#pragma unroll
      for (int ks = 0; ks < 2; ++ks)
        vf[hh][nt][ks] = *(const bf16x8*)(vsb + (hh * 32 + nt * 16 + c16) * VS_ROW_B + ks * 64 + g4 * 16);
  asm volatile("s_waitcnt lgkmcnt(0)" ::: "memory");
  __builtin_amdgcn_sched_barrier(0x20);

#pragma unroll
  for (int qk = 0; qk < 2; ++qk) {
    const int rowbase = qk * 256 + 64 * wave;
    const int koff = qk * 64;
    const __bf16* Ap0 = wqkv + (size_t)(rowbase + l31) * 256 + g2 * 8;
    const __bf16* Ap1 = Ap0 + 32 * 256;
    f32x16 a00 = zero16(), a01 = zero16(), a10 = zero16(), a11 = zero16();
    __builtin_amdgcn_s_setprio(1);
#pragma unroll
    for (int ks = 0; ks < 16; ++ks) {
      bf16x8 A0 = *(const bf16x8*)(Ap0 + ks * 16);
      bf16x8 A1 = *(const bf16x8*)(Ap1 + ks * 16);
      a00 = __builtin_amdgcn_mfma_f32_32x32x16_bf16(A0, Bf0[ks], a00, 0, 0, 0);
      a01 = __builtin_amdgcn_mfma_f32_32x32x16_bf16(A0, Bf1[ks], a01, 0, 0, 0);
      a10 = __builtin_amdgcn_mfma_f32_32x32x16_bf16(A1, Bf0[ks], a10, 0, 0, 0);
      a11 = __builtin_amdgcn_mfma_f32_32x32x16_bf16(A1, Bf1[ks], a11, 0, 0, 0);
    }
    __builtin_amdgcn_s_setprio(0);
#define STORE_QK(ACC, P_, NT)                                                  \
    {                                                                          \
      const int n_ = (NT) * 32 + l31;                                          \
      _Pragma("unroll") for (int rb = 0; rb < 4; ++rb) {                       \
        const int ddb = koff + (P_) * 32 + rb * 8 + g2 * 4;                    \
        bf16x4 v4;                                                             \
        v4[0] = (__bf16)ACC[rb * 4 + 0]; v4[1] = (__bf16)ACC[rb * 4 + 1];      \
        v4[2] = (__bf16)ACC[rb * 4 + 2]; v4[3] = (__bf16)ACC[rb * 4 + 3];      \
        *(bf16x4*)(slice + n_ * QK_ROW_B + ddb * 2) = v4;                      \
      }                                                                        \
    }
    STORE_QK(a00, 0, 0)
    STORE_QK(a01, 0, 1)
    STORE_QK(a10, 1, 0)
    STORE_QK(a11, 1, 1)
  }
  bf16x8 qf[2][4], kf[2][4];
#pragma unroll
  for (int hh = 0; hh < 2; ++hh)
#pragma unroll
    for (int t = 0; t < 4; ++t) {
      qf[hh][t] = *(const bf16x8*)(slice + (t * 16 + c16) * QK_ROW_B + hh * 64 + g4 * 16);
      kf[hh][t] = *(const bf16x8*)(slice + (t * 16 + c16) * QK_ROW_B + 128 + hh * 64 + g4 * 16);
    }
  asm volatile("s_waitcnt lgkmcnt(0)" ::: "memory");
  __builtin_amdgcn_sched_barrier(0x20);

  f32x4 pacc[2][4][2];
  char* Pb0 = slice;
  char* Pb1 = slice + 8192;
  {
    const f32x4 z4 = {0.f, 0.f, 0.f, 0.f};
    f32x4 dacc[2][4][4];
    __builtin_amdgcn_s_setprio(1);
#pragma unroll
    for (int hh = 0; hh < 2; ++hh)
#pragma unroll
      for (int mt = 0; mt < 4; ++mt)
#pragma unroll
        for (int nt = 0; nt < 4; ++nt)
          dacc[hh][mt][nt] = __builtin_amdgcn_mfma_f32_16x16x32_bf16(qf[hh][mt], kf[hh][nt], z4, 0, 0, 0);
    __builtin_amdgcn_s_setprio(0);

    const int h0 = wave * 2;
#pragma unroll
    for (int mt = 0; mt < 4; ++mt) {
#pragma unroll
      for (int r = 0; r < 4; ++r) {
        const int i = mt * 16 + g4 * 4 + r;
        float p0[4], p1[4], s0 = 0.f, s1 = 0.f;
#pragma unroll
        for (int nt = 0; nt < 4; ++nt) {
          const int j = nt * 16 + c16;
          float v0 = dacc[0][mt][nt][r] * SCALE_F;
          float v1 = dacc[1][mt][nt][r] * SCALE_F;
          if (j < NPOS) {
            if (i < NPOS) { const float bb = bias_s[i * 49 + j]; v0 += bb; v1 += bb; }
          } else {
            v0 = -1e30f; v1 = -1e30f;
          }
          p0[nt] = __expf(v0); s0 += p0[nt];
          p1[nt] = __expf(v1); s1 += p1[nt];
        }
        s0 += __shfl_xor(s0, 1); s1 += __shfl_xor(s1, 1);
        s0 += __shfl_xor(s0, 2); s1 += __shfl_xor(s1, 2);
        s0 += __shfl_xor(s0, 4); s1 += __shfl_xor(s1, 4);
        s0 += __shfl_xor(s0, 8); s1 += __shfl_xor(s1, 8);
        const float inv0 = 1.f / s0, inv1 = 1.f / s1;
        if (i < NPOS) {
          float* ap0 = attng + ((size_t)(work * NHEADS + h0) * 49 + i) * 49;
          float* ap1 = ap0 + 49 * 49;
#pragma unroll
          for (int nt = 0; nt < 4; ++nt) {
            const int j = nt * 16 + c16;
            if (j < NPOS) { ap0[j] = p0[nt] * inv0; ap1[j] = p1[nt] * inv1; }
          }
        }
#pragma unroll
        for (int nt = 0; nt < 4; ++nt) {
          const int j = nt * 16 + c16;
          *(__bf16*)(Pb0 + i * 128 + 16 * ((j >> 3) ^ (i & 7)) + 2 * (j & 7)) = (__bf16)(p0[nt] * inv0);
          *(__bf16*)(Pb1 + i * 128 + 16 * ((j >> 3) ^ (i & 7)) + 2 * (j & 7)) = (__bf16)(p1[nt] * inv1);
        }
      }
    }

    __builtin_amdgcn_s_setprio(1);
#pragma unroll
    for (int hh = 0; hh < 2; ++hh) {
      char* Pb = hh ? Pb1 : Pb0;
#pragma unroll
      for (int mt = 0; mt < 4; ++mt) {
        const int i = mt * 16 + c16;
        bf16x8 pa0 = *(const bf16x8*)(Pb + i * 128 + 16 * ((0 + g4) ^ (i & 7)));
        bf16x8 pa1 = *(const bf16x8*)(Pb + i * 128 + 16 * ((4 + g4) ^ (i & 7)));
#pragma unroll
        for (int nt = 0; nt < 2; ++nt) {
          f32x4 acc = {0.f, 0.f, 0.f, 0.f};
          acc = __builtin_amdgcn_mfma_f32_16x16x32_bf16(pa0, vf[hh][nt][0], acc, 0, 0, 0);
          acc = __builtin_amdgcn_mfma_f32_16x16x32_bf16(pa1, vf[hh][nt][1], acc, 0, 0, 0);
          pacc[hh][mt][nt] = acc;
        }
      }
    }
    __builtin_amdgcn_s_setprio(0);
  }

  if constexpr (MODE == 1) {
    __bf16* ag = aoT_g + (size_t)work * 12544;
#pragma unroll
    for (int hh = 0; hh < 2; ++hh) {
      const int h = wave * 2 + hh;
#pragma unroll
      for (int mt = 0; mt < 4; ++mt)
#pragma unroll
        for (int e = 0; e < 4; ++e) {
          const int pos = mt * 16 + g4 * 4 + e;
          if (pos < NPOS) {
            ag[pos * 256 + h * 32 + c16]      = (__bf16)pacc[hh][mt][0][e];
            ag[pos * 256 + h * 32 + 16 + c16] = (__bf16)pacc[hh][mt][1][e];
          }
        }
    }
  } else {
    __syncthreads();
#pragma unroll
    for (int hh = 0; hh < 2; ++hh) {
      const int h = wave * 2 + hh;
#pragma unroll
      for (int mt = 0; mt < 4; ++mt)
#pragma unroll
        for (int nt = 0; nt < 2; ++nt)
#pragma unroll
          for (int e = 0; e < 4; ++e) {
            const int i = mt * 16 + g4 * 4 + e;
            const int cc = h * 32 + nt * 16 + c16;
            aoT[i * AOT_PITCH + cc] = (__bf16)pacc[hh][mt][nt][e];
          }
    }
    __syncthreads();
    {
      bf16x8 Cf0[16], Cf1[16];
      const __bf16* Bp = aoT + l31 * AOT_PITCH + g2 * 8;
#pragma unroll
      for (int ks = 0; ks < 16; ++ks) {
        Cf0[ks] = *(const bf16x8*)(Bp + ks * 16);
        Cf1[ks] = *(const bf16x8*)(Bp + 32 * AOT_PITCH + ks * 16);
      }
      const __bf16* Ap0 = wo + (size_t)(wave * 64 + l31) * 256 + g2 * 8;
      const __bf16* Ap1 = Ap0 + 32 * 256;
      f32x16 a00 = zero16(), a01 = zero16(), a10 = zero16(), a11 = zero16();
      __builtin_amdgcn_s_setprio(1);
#pragma unroll
      for (int ks = 0; ks < 16; ++ks) {
        bf16x8 A0 = *(const bf16x8*)(Ap0 + ks * 16);
        bf16x8 A1 = *(const bf16x8*)(Ap1 + ks * 16);
        a00 = __builtin_amdgcn_mfma_f32_32x32x16_bf16(A0, Cf0[ks], a00, 0, 0, 0);
        a01 = __builtin_amdgcn_mfma_f32_32x32x16_bf16(A0, Cf1[ks], a01, 0, 0, 0);
        a10 = __builtin_amdgcn_mfma_f32_32x32x16_bf16(A1, Cf0[ks], a10, 0, 0, 0);
        a11 = __builtin_amdgcn_mfma_f32_32x32x16_bf16(A1, Cf1[ks], a11, 0, 0, 0);
      }
      __builtin_amdgcn_s_setprio(0);
      float* og = outg + (size_t)b * 256 * 12544;
#define STORE_OUT(ACC, MT, NT)                                                    \
      {                                                                           \
        const int n_ = (NT) * 32 + l31;                                           \
        if (n_ < NPOS) {                                                          \
          const int pr_ = n_ / 7, pc_ = n_ - pr_ * 7;                             \
          float* orow = og + (size_t)(r0 + pr_) * 112 + (c0 + pc_);               \
          _Pragma("unroll") for (int rg = 0; rg < 16; ++rg) {                     \
            const int o2 = wave * 64 + (MT) * 32 + (rg & 3) + 8 * (rg >> 2) + 4 * g2; \
            orow[(size_t)o2 * 12544] = ACC[rg] + bo_s[o2];                        \
          }                                                                       \
        }                                                                         \
      }
      STORE_OUT(a00, 0, 0)
      STORE_OUT(a01, 0, 1)
      STORE_OUT(a10, 1, 0)
      STORE_OUT(a11, 1, 1)
    }
  }
}

// ---------------- oproj: out[b][oc][row][0..111] = Wo @ attn_out + bo ----------------
__global__ __launch_bounds__(256, 2) void oproj_kernel(
    const __bf16* __restrict__ aoT_g, const __bf16* __restrict__ wo,
    const float* __restrict__ bo_g, float* __restrict__ outg) {
  __shared__ __bf16 aoB[112 * 264];
  __shared__ float bo_s[256];
  const int tid = threadIdx.x;
  const int bid = blockIdx.x;
  const int work = (bid & 7) * 224 + (bid >> 3);
  const int pr = work % 7;
  const int g  = work / 7;
  const int i1 = g & 15, b = g >> 4;
  const int wave = tid >> 6, lane = tid & 63;
  const int c16 = lane & 15, g4 = lane >> 4;

  {
    const int rr = tid >> 5, coff = (tid & 31) * 8;
#pragma unroll
    for (int it = 0; it < 14; ++it) {
      const int gr = it * 8 + rr;
      const int i2 = gr / 7, pc = gr - i2 * 7;
      const size_t src = ((size_t)((b * 256 + i1 * 16 + i2) * 49 + pr * 7 + pc)) * 256 + coff;
      *(bf16x8*)(aoB + gr * 264 + coff) = *(const bf16x8*)(aoT_g + src);
    }
    bo_s[tid] = bo_g[tid];
  }
  __syncthreads();

  const int oc0 = wave * 64;
  f32x4 acc[4][7];
#pragma unroll
  for (int mt = 0; mt < 4; ++mt)
#pragma unroll
    for (int nt = 0; nt < 7; ++nt) acc[mt][nt] = f32x4{0.f, 0.f, 0.f, 0.f};
#pragma unroll
  for (int kk = 0; kk < 8; ++kk) {
    bf16x8 Af[4], Bf[7];
#pragma unroll
    for (int mt = 0; mt < 4; ++mt)
      Af[mt] = *(const bf16x8*)(wo + (size_t)(oc0 + mt * 16 + c16) * 256 + kk * 32 + g4 * 8);
#pragma unroll
    for (int nt = 0; nt < 7; ++nt)
      Bf[nt] = *(const bf16x8*)(aoB + (nt * 16 + c16) * 264 + kk * 32 + g4 * 8);
    __builtin_amdgcn_s_setprio(1);
#pragma unroll
    for (int mt = 0; mt < 4; ++mt)
#pragma unroll
      for (int nt = 0; nt < 7; ++nt)
        acc[mt][nt] = __builtin_amdgcn_mfma_f32_16x16x32_bf16(Af[mt], Bf[nt], acc[mt][nt], 0, 0, 0);
    __builtin_amdgcn_s_setprio(0);
  }
  float* orow = outg + (size_t)b * 256 * 12544 + (size_t)(i1 * 7 + pr) * 112;
#pragma unroll
  for (int mt = 0; mt < 4; ++mt)
#pragma unroll
    for (int e = 0; e < 4; ++e) {
      const int oc = oc0 + mt * 16 + g4 * 4 + e;
      const float bb = bo_s[oc];
#pragma unroll
      for (int nt = 0; nt < 7; ++nt)
        orow[(size_t)oc * 12544 + nt * 16 + c16] = acc[mt][nt][e] + bb;
    }
}

extern "C" void kernel_launch(void* const* d_in, const int* in_sizes, int n_in,
                              void* d_out, int out_size, void* d_ws, size_t ws_size,
                              hipStream_t stream) {
  const float* x   = (const float*)d_in[0];
  const float* Wq  = (const float*)d_in[1];
  const float* Wkv = (const float*)d_in[2];
  const float* Wo  = (const float*)d_in[3];
  const float* bo  = (const float*)d_in[4];
  const float* pos = (const float*)d_in[5];
  const int*   rel = (const int*)d_in[6];

  float* outg  = (float*)d_out;
  float* attng = outg + (size_t)16 * 256 * 112 * 112;

  __bf16* wqkv = (__bf16*)d_ws;
  __bf16* wo   = wqkv + 768 * 256;
  float*  bias = (float*)(wo + 256 * 256);

  size_t base = 768 * 256 * 2 + 256 * 256 * 2 + 2401 * 4;
  base = (base + 255) & ~(size_t)255;
  const size_t ao_bytes = (size_t)4096 * 12544 * 2;
  const size_t qk_bytes = (size_t)4096 * 8 * 3136;   // q or k: [win][h][49][32] bf16
  const size_t vt_bytes = (size_t)4096 * 8 * 4096;   // vT: [win][h][32][64] bf16
  const size_t q_off = base + ao_bytes;
  const size_t k_off = q_off + qk_bytes;
  const size_t v_off = k_off + qk_bytes;
  const size_t full  = v_off + vt_bytes;

  __bf16* aoT_g = (__bf16*)((char*)d_ws + base);
  __bf16* qg    = (__bf16*)((char*)d_ws + q_off);
  __bf16* kg    = (__bf16*)((char*)d_ws + k_off);
  __bf16* vtg   = (__bf16*)((char*)d_ws + v_off);

  hipFuncSetAttribute((const void*)attn_kernel<0>,
                      hipFuncAttributeMaxDynamicSharedMemorySize, LDS_BYTES);
  hipFuncSetAttribute((const void*)attn_kernel<1>,
                      hipFuncAttributeMaxDynamicSharedMemorySize, LDS_BYTES);
  hipFuncSetAttribute((const void*)qkv_kernel,
                      hipFuncAttributeMaxDynamicSharedMemorySize, QKV_LDS);
  hipFuncSetAttribute((const void*)att_kernel,
                      hipFuncAttributeMaxDynamicSharedMemorySize, ATT_LDS);

  prep_kernel<<<dim3(512), dim3(256), 0, stream>>>(Wq, Wkv, Wo, pos, rel, wqkv, wo, bias);
  if (ws_size >= full) {
    qkv_kernel<<<dim3(4096), dim3(256), QKV_LDS, stream>>>(x, wqkv, qg, kg, vtg);
    att_kernel<<<dim3(8192), dim3(256), ATT_LDS, stream>>>(qg, kg, vtg, bias, attng, aoT_g);
    oproj_kernel<<<dim3(1792), dim3(256), 0, stream>>>(aoT_g, wo, bo, outg);
  } else if (ws_size >= base + ao_bytes) {
    attn_kernel<1><<<dim3(4096), dim3(256), LDS_BYTES, stream>>>(
        x, wqkv, wo, bias, bo, outg, attng, aoT_g);
    oproj_kernel<<<dim3(1792), dim3(256), 0, stream>>>(aoT_g, wo, bo, outg);
  } else {
    attn_kernel<0><<<dim3(4096), dim3(256), LDS_BYTES, stream>>>(
        x, wqkv, wo, bias, bo, outg, attng, nullptr);
  }
}

// Round 7
// 574.913 us; speedup vs baseline: 1.0525x; 1.0525x over previous
//
#include <hip/hip_runtime.h>
#include <hip/hip_bf16.h>

typedef __bf16 bf16x8 __attribute__((ext_vector_type(8)));
typedef __bf16 bf16x4 __attribute__((ext_vector_type(4)));
typedef float  f32x4  __attribute__((ext_vector_type(4)));
typedef float  f32x16 __attribute__((ext_vector_type(16)));
typedef float  f32x4a __attribute__((ext_vector_type(4))) __attribute__((aligned(4)));
typedef float  f32x2a __attribute__((ext_vector_type(2))) __attribute__((aligned(4)));

#define NPOS 49
#define NHEADS 8
#define SCALE_F 0.17677669529663687f

// ---- legacy (round-5) LDS layout ----
#define SLICE_B   16896
#define QK_ROW_B  264
#define VS_OFF    8192
#define VS_ROW_B  136
#define XWT_PITCH 264
#define AOT_PITCH 264
#define BIAS_OFF  67584
#define BO_OFF    77188
#define LDS_BYTES 78212

// ---- qkv kernel ----
#define XW2_PITCH 268                    // elements; 536 B rows -> 2-way-max LDS banking
#define QKV_LDS   (64 * XW2_PITCH * 2)   // 34304 B
#define ATT_LDS   (4 * 8192)             // 32768 B (4 P-buffers)

static __device__ __forceinline__ f32x16 zero16() {
  f32x16 z;
#pragma unroll
  for (int i = 0; i < 16; ++i) z[i] = 0.f;
  return z;
}

__global__ void prep_kernel(const float* __restrict__ Wq, const float* __restrict__ Wkv,
                            const float* __restrict__ Wo, const float* __restrict__ pos,
                            const int* __restrict__ rel, __bf16* __restrict__ wqkv,
                            __bf16* __restrict__ wo, float* __restrict__ bias) {
  int idx = blockIdx.x * 256 + threadIdx.x;
  if (idx < 256 * 256) wqkv[idx] = (__bf16)Wq[idx];              // q rows 0..255
  if (idx < 512 * 256) wqkv[256 * 256 + idx] = (__bf16)Wkv[idx]; // k 256..511, v 512..767
  if (idx < 256 * 256) wo[idx] = (__bf16)Wo[idx];
  if (idx < 49 * 49) bias[idx] = pos[rel[idx * 2] * 13 + rel[idx * 2 + 1]];
}

// =====================================================================
// kernel 1: qkv projection. One block per window, 4 waves.
// Staging: thread handles 7 (ch,row) pairs, each = dwordx4+dwordx2+dword
// (21 wide loads, 7 independent chains) -> LDS transpose to [pos][ch].
// GEMM: 3 strip-pairs per wave, fully unrolled for cross-pair overlap.
// =====================================================================
__global__ __launch_bounds__(256, 4) void qkv_kernel(
    const float* __restrict__ x, const __bf16* __restrict__ wqkv,
    __bf16* __restrict__ qg, __bf16* __restrict__ kg, __bf16* __restrict__ vtg) {
  extern __shared__ char smem[];
  __bf16* xwT = (__bf16*)smem;

  const int tid = threadIdx.x;
  const int bid = blockIdx.x;
  const int work = (bid & 7) * 512 + (bid >> 3);  // XCD swizzle
  const int b  = work >> 8;
  const int i1 = (work >> 4) & 15;
  const int i2 = work & 15;
  const int r0 = i1 * 7, c0 = i2 * 7;
  const int wave = tid >> 6, lane = tid & 63;
  const int l31 = lane & 31, g2 = lane >> 5;

  // zero-fill pad rows 49..63 (cols 0..255) — v of padded positions must be 0
  {
    bf16x8 z8;
#pragma unroll
    for (int j = 0; j < 8; ++j) z8[j] = (__bf16)0.f;
    for (int i = tid; i < 480; i += 256) {
      const int row = 49 + (i >> 5);
      const int col = (i & 31) * 8;
      *(bf16x8*)(xwT + row * XW2_PITCH + col) = z8;
    }
  }

  // gather x window: 1792 (ch,row) pairs; 7 per thread; wide loads
  {
    f32x4a b4[7]; f32x2a b2[7]; float b1[7];
    int chv[7], rowv[7];
    const float* xb = x + (size_t)b * 256 * 12544;
#pragma unroll
    for (int k = 0; k < 7; ++k) {
      const int p = k * 256 + tid;
      const int ch = p / 7;                 // magic-mul
      const int row = p - ch * 7;
      chv[k] = ch; rowv[k] = row;
      const float* xr = xb + (size_t)ch * 12544 + (size_t)(r0 + row) * 112 + c0;
      b4[k] = *(const f32x4a*)xr;
      b2[k] = *(const f32x2a*)(xr + 4);
      b1[k] = xr[6];
    }
#pragma unroll
    for (int k = 0; k < 7; ++k) {
      __bf16* dst = xwT + (rowv[k] * 7) * XW2_PITCH + chv[k];
      dst[0 * XW2_PITCH] = (__bf16)b4[k][0];
      dst[1 * XW2_PITCH] = (__bf16)b4[k][1];
      dst[2 * XW2_PITCH] = (__bf16)b4[k][2];
      dst[3 * XW2_PITCH] = (__bf16)b4[k][3];
      dst[4 * XW2_PITCH] = (__bf16)b2[k][0];
      dst[5 * XW2_PITCH] = (__bf16)b2[k][1];
      dst[6 * XW2_PITCH] = (__bf16)b1[k];
    }
  }
  __syncthreads();

  const size_t hb = (size_t)work * 8;

#pragma unroll
  for (int p = 3 * wave; p < 3 * wave + 3; ++p) {
    const __bf16* Ap0 = wqkv + (size_t)(64 * p + l31) * 256 + g2 * 8;
    const __bf16* Ap1 = Ap0 + 32 * 256;
    const __bf16* Bp  = xwT + l31 * XW2_PITCH + g2 * 8;
    f32x16 a00 = zero16(), a01 = zero16(), a10 = zero16(), a11 = zero16();
    __builtin_amdgcn_s_setprio(1);
#pragma unroll
    for (int ks = 0; ks < 16; ++ks) {
      bf16x8 B0 = *(const bf16x8*)(Bp + ks * 16);
      bf16x8 B1 = *(const bf16x8*)(Bp + 32 * XW2_PITCH + ks * 16);
      bf16x8 A0 = *(const bf16x8*)(Ap0 + ks * 16);
      bf16x8 A1 = *(const bf16x8*)(Ap1 + ks * 16);
      a00 = __builtin_amdgcn_mfma_f32_32x32x16_bf16(A0, B0, a00, 0, 0, 0);
      a01 = __builtin_amdgcn_mfma_f32_32x32x16_bf16(A0, B1, a01, 0, 0, 0);
      a10 = __builtin_amdgcn_mfma_f32_32x32x16_bf16(A1, B0, a10, 0, 0, 0);
      a11 = __builtin_amdgcn_mfma_f32_32x32x16_bf16(A1, B1, a11, 0, 0, 0);
    }
    __builtin_amdgcn_s_setprio(0);
#define QKV_STORE(ACC, S, NT)                                                  \
    {                                                                          \
      const int sec = (S) >> 3, h = (S) & 7;                                   \
      const int n_ = (NT) * 32 + l31;                                          \
      if (sec < 2) {                                                           \
        if (n_ < NPOS) {                                                       \
          __bf16* bp = (sec ? kg : qg) + (hb + h) * 1568 + n_ * 32;            \
          _Pragma("unroll") for (int rb = 0; rb < 4; ++rb) {                   \
            bf16x4 v4;                                                         \
            v4[0] = (__bf16)ACC[rb * 4 + 0]; v4[1] = (__bf16)ACC[rb * 4 + 1];  \
            v4[2] = (__bf16)ACC[rb * 4 + 2]; v4[3] = (__bf16)ACC[rb * 4 + 3];  \
            *(bf16x4*)(bp + 8 * rb + 4 * g2) = v4;                             \
          }                                                                    \
        }                                                                      \
      } else {                                                                 \
        __bf16* vp = vtg + (hb + h) * 2048 + n_;                               \
        _Pragma("unroll") for (int rg = 0; rg < 16; ++rg) {                    \
          const int dd = (rg & 3) + 8 * (rg >> 2) + 4 * g2;                    \
          vp[dd * 64] = (__bf16)ACC[rg];                                       \
        }                                                                      \
      }                                                                        \
    }
    QKV_STORE(a00, 2 * p, 0)
    QKV_STORE(a01, 2 * p, 1)
    QKV_STORE(a10, 2 * p + 1, 0)
    QKV_STORE(a11, 2 * p + 1, 1)
  }
}

// =====================================================================
// kernel 2: attention. One wave per (window, head); 4 waves/block;
// no __syncthreads. P lives in an 8 KB per-wave LDS buffer.
// =====================================================================
__global__ __launch_bounds__(256, 3) void att_kernel(
    const __bf16* __restrict__ qg, const __bf16* __restrict__ kg,
    const __bf16* __restrict__ vtg, const float* __restrict__ bias_g,
    float* __restrict__ attng, __bf16* __restrict__ aoT_g) {
  extern __shared__ char smem[];
  const int tid = threadIdx.x;
  const int bid = blockIdx.x;
  const int work = (bid & 7) * 1024 + (bid >> 3);  // XCD swizzle, 8192 blocks
  const int win  = work >> 1;
  const int wave = tid >> 6, lane = tid & 63;
  const int head = (work & 1) * 4 + wave;
  const int c16 = lane & 15, g4 = lane >> 4;
  char* Pb = smem + wave * 8192;

  const size_t hidx = (size_t)win * 8 + head;
  const __bf16* qb = qg + hidx * 1568;
  const __bf16* kb = kg + hidx * 1568;
  const __bf16* vb = vtg + hidx * 2048;

  bf16x8 qf[4], kf[4];
#pragma unroll
  for (int t = 0; t < 4; ++t) {
    int rr = t * 16 + c16; rr = rr > 48 ? 48 : rr;
    qf[t] = *(const bf16x8*)(qb + rr * 32 + g4 * 8);
    kf[t] = *(const bf16x8*)(kb + rr * 32 + g4 * 8);
  }
  bf16x8 vf[2][2];
#pragma unroll
  for (int nt = 0; nt < 2; ++nt)
#pragma unroll
    for (int ks = 0; ks < 2; ++ks)
      vf[nt][ks] = *(const bf16x8*)(vb + (nt * 16 + c16) * 64 + ks * 32 + g4 * 8);

  f32x4 dacc[4][4];
  const f32x4 z4 = {0.f, 0.f, 0.f, 0.f};
  __builtin_amdgcn_s_setprio(1);
#pragma unroll
  for (int mt = 0; mt < 4; ++mt)
#pragma unroll
    for (int nt = 0; nt < 4; ++nt)
      dacc[mt][nt] = __builtin_amdgcn_mfma_f32_16x16x32_bf16(qf[mt], kf[nt], z4, 0, 0, 0);
  __builtin_amdgcn_s_setprio(0);

  // softmax (no max-subtraction: scores are O(1); identical to reference math)
#pragma unroll
  for (int mt = 0; mt < 4; ++mt) {
#pragma unroll
    for (int r = 0; r < 4; ++r) {
      const int i = mt * 16 + g4 * 4 + r;
      float p[4], s = 0.f;
#pragma unroll
      for (int nt = 0; nt < 4; ++nt) {
        const int j = nt * 16 + c16;
        float val = dacc[mt][nt][r] * SCALE_F;
        if (j < NPOS) {
          if (i < NPOS) val += bias_g[i * 49 + j];
        } else {
          val = -1e30f;
        }
        p[nt] = __expf(val); s += p[nt];
      }
      s += __shfl_xor(s, 1); s += __shfl_xor(s, 2);
      s += __shfl_xor(s, 4); s += __shfl_xor(s, 8);
      const float inv = 1.f / s;
      if (i < NPOS) {
        float* ap = attng + ((size_t)(win * NHEADS + head) * 49 + i) * 49;
#pragma unroll
        for (int nt = 0; nt < 4; ++nt) {
          const int j = nt * 16 + c16;
          if (j < NPOS) ap[j] = p[nt] * inv;
        }
      }
#pragma unroll
      for (int nt = 0; nt < 4; ++nt) {
        const int j = nt * 16 + c16;
        *(__bf16*)(Pb + i * 128 + 16 * ((j >> 3) ^ (i & 7)) + 2 * (j & 7)) = (__bf16)(p[nt] * inv);
      }
    }
  }

  // PV
  f32x4 pacc[4][2];
  __builtin_amdgcn_s_setprio(1);
#pragma unroll
  for (int mt = 0; mt < 4; ++mt) {
    const int i = mt * 16 + c16;
    bf16x8 pa0 = *(const bf16x8*)(Pb + i * 128 + 16 * ((0 + g4) ^ (i & 7)));
    bf16x8 pa1 = *(const bf16x8*)(Pb + i * 128 + 16 * ((4 + g4) ^ (i & 7)));
#pragma unroll
    for (int nt = 0; nt < 2; ++nt) {
      f32x4 acc = {0.f, 0.f, 0.f, 0.f};
      acc = __builtin_amdgcn_mfma_f32_16x16x32_bf16(pa0, vf[nt][0], acc, 0, 0, 0);
      acc = __builtin_amdgcn_mfma_f32_16x16x32_bf16(pa1, vf[nt][1], acc, 0, 0, 0);
      pacc[mt][nt] = acc;
    }
  }
  __builtin_amdgcn_s_setprio(0);

  __bf16* ag = aoT_g + (size_t)win * 12544;
#pragma unroll
  for (int mt = 0; mt < 4; ++mt)
#pragma unroll
    for (int e = 0; e < 4; ++e) {
      const int pos = mt * 16 + g4 * 4 + e;
      if (pos < NPOS) {
        ag[pos * 256 + head * 32 + c16]      = (__bf16)pacc[mt][0][e];
        ag[pos * 256 + head * 32 + 16 + c16] = (__bf16)pacc[mt][1][e];
      }
    }
}

// =====================================================================
// LEGACY fallback (round-5): monolithic / split attn kernel
// =====================================================================
template <int MODE>
__global__ __launch_bounds__(256, 2) void attn_kernel(
    const float* __restrict__ x, const __bf16* __restrict__ wqkv,
    const __bf16* __restrict__ wo, const float* __restrict__ bias_g,
    const float* __restrict__ bo_g, float* __restrict__ outg,
    float* __restrict__ attng, __bf16* __restrict__ aoT_g) {
  extern __shared__ char smem[];
  __bf16* xwT = (__bf16*)smem;
  __bf16* aoT = (__bf16*)smem;
  float* bias_s = (float*)(smem + BIAS_OFF);
  float* bo_s   = (float*)(smem + BO_OFF);

  const int tid = threadIdx.x;
  const int bid = blockIdx.x;
  const int work = (bid & 7) * 512 + (bid >> 3);
  const int b  = work >> 8;
  const int i1 = (work >> 4) & 15;
  const int i2 = work & 15;
  const int r0 = i1 * 7, c0 = i2 * 7;
  const int wave = tid >> 6, lane = tid & 63;
  const int l31 = lane & 31, g2 = lane >> 5;
  const int c16 = lane & 15, g4 = lane >> 4;
  char* slice = smem + wave * SLICE_B;

  {
    const int n = tid & 63, cb = tid >> 6;
    const int np = (n < NPOS) ? n : 0;
    const float zf = (n < NPOS) ? 1.f : 0.f;
    const int pr = np / 7, pc = np - pr * 7;
    const float* xg = x + (size_t)b * 256 * 12544 + (size_t)(r0 + pr) * 112 + (c0 + pc);
    float tmp[64];
#pragma unroll
    for (int it = 0; it < 64; ++it)
      tmp[it] = xg[(size_t)(it * 4 + cb) * 12544];
#pragma unroll
    for (int it = 0; it < 64; ++it)
      xwT[n * XWT_PITCH + it * 4 + cb] = (__bf16)(tmp[it] * zf);
    const float4* bg4 = (const float4*)bias_g;
    for (int i = tid; i < 600; i += 256) ((float4*)bias_s)[i] = bg4[i];
    if (tid == 0) bias_s[2400] = bias_g[2400];
    if constexpr (MODE == 0) bo_s[tid] = bo_g[tid];
  }
  __syncthreads();

  bf16x8 Bf0[16], Bf1[16];
  {
    const __bf16* Bp = xwT + l31 * XWT_PITCH + g2 * 8;
#pragma unroll
    for (int ks = 0; ks < 16; ++ks) {
      Bf0[ks] = *(const bf16x8*)(Bp + ks * 16);
      Bf1[ks] = *(const bf16x8*)(Bp + 32 * XWT_PITCH + ks * 16);
    }
  }
  __syncthreads();

  char* vsb = slice + VS_OFF;
  {
    const __bf16* Ap0 = wqkv + (size_t)(512 + 64 * wave + l31) * 256 + g2 * 8;
    const __bf16* Ap1 = Ap0 + 32 * 256;
    f32x16 a00 = zero16(), a01 = zero16(), a10 = zero16(), a11 = zero16();
    __builtin_amdgcn_s_setprio(1);
#pragma unroll
    for (int ks = 0; ks < 16; ++ks) {
      bf16x8 A0 = *(const bf16x8*)(Ap0 + ks * 16);
      bf16x8 A1 = *(const bf16x8*)(Ap1 + ks * 16);
      a00 = __builtin_amdgcn_mfma_f32_32x32x16_bf16(A0, Bf0[ks], a00, 0, 0, 0);
      a01 = __builtin_amdgcn_mfma_f32_32x32x16_bf16(A0, Bf1[ks], a01, 0, 0, 0);
      a10 = __builtin_amdgcn_mfma_f32_32x32x16_bf16(A1, Bf0[ks], a10, 0, 0, 0);
      a11 = __builtin_amdgcn_mfma_f32_32x32x16_bf16(A1, Bf1[ks], a11, 0, 0, 0);
    }
    __builtin_amdgcn_s_setprio(0);
#pragma unroll
    for (int rg = 0; rg < 16; ++rg) {
      const int dd = (rg & 3) + 8 * (rg >> 2) + 4 * g2;
      *(__bf16*)(vsb + dd * VS_ROW_B + l31 * 2)              = (__bf16)a00[rg];
      *(__bf16*)(vsb + dd * VS_ROW_B + 64 + l31 * 2)         = (__bf16)a01[rg];
      *(__bf16*)(vsb + (32 + dd) * VS_ROW_B + l31 * 2)       = (__bf16)a10[rg];
      *(__bf16*)(vsb + (32 + dd) * VS_ROW_B + 64 + l31 * 2)  = (__bf16)a11[rg];
    }
  }
  bf16x8 vf[2][2][2];
#pragma unroll
  for (int hh = 0; hh < 2; ++hh)
#pragma unroll
    for (int nt = 0; nt < 2; ++nt)
#pragma unroll
      for (int ks = 0; ks < 2; ++ks)
        vf[hh][nt][ks] = *(const bf16x8*)(vsb + (hh * 32 + nt * 16 + c16) * VS_ROW_B + ks * 64 + g4 * 16);
  asm volatile("s_waitcnt lgkmcnt(0)" ::: "memory");
  __builtin_amdgcn_sched_barrier(0x20);

#pragma unroll
  for (int qk = 0; qk < 2; ++qk) {
    const int rowbase = qk * 256 + 64 * wave;
    const int koff = qk * 64;
    const __bf16* Ap0 = wqkv + (size_t)(rowbase + l31) * 256 + g2 * 8;
    const __bf16* Ap1 = Ap0 + 32 * 256;
    f32x16 a00 = zero16(), a01 = zero16(), a10 = zero16(), a11 = zero16();
    __builtin_amdgcn_s_setprio(1);
#pragma unroll
    for (int ks = 0; ks < 16; ++ks) {
      bf16x8 A0 = *(const bf16x8*)(Ap0 + ks * 16);
      bf16x8 A1 = *(const bf16x8*)(Ap1 + ks * 16);
      a00 = __builtin_amdgcn_mfma_f32_32x32x16_bf16(A0, Bf0[ks], a00, 0, 0, 0);
      a01 = __builtin_amdgcn_mfma_f32_32x32x16_bf16(A0, Bf1[ks], a01, 0, 0, 0);
      a10 = __builtin_amdgcn_mfma_f32_32x32x16_bf16(A1, Bf0[ks], a10, 0, 0, 0);
      a11 = __builtin_amdgcn_mfma_f32_32x32x16_bf16(A1, Bf1[ks], a11, 0, 0, 0);
    }
    __builtin_amdgcn_s_setprio(0);
#define STORE_QK(ACC, P_, NT)                                                  \
    {                                                                          \
      const int n_ = (NT) * 32 + l31;                                          \
      _Pragma("unroll") for (int rb = 0; rb < 4; ++rb) {                       \
        const int ddb = koff + (P_) * 32 + rb * 8 + g2 * 4;                    \
        bf16x4 v4;                                                             \
        v4[0] = (__bf16)ACC[rb * 4 + 0]; v4[1] = (__bf16)ACC[rb * 4 + 1];      \
        v4[2] = (__bf16)ACC[rb * 4 + 2]; v4[3] = (__bf16)ACC[rb * 4 + 3];      \
        *(bf16x4*)(slice + n_ * QK_ROW_B + ddb * 2) = v4;                      \
      }                                                                        \
    }
    STORE_QK(a00, 0, 0)
    STORE_QK(a01, 0, 1)
    STORE_QK(a10, 1, 0)
    STORE_QK(a11, 1, 1)
  }
  bf16x8 qf[2][4], kf[2][4];
#pragma unroll
  for (int hh = 0; hh < 2; ++hh)
#pragma unroll
    for (int t = 0; t < 4; ++t) {
      qf[hh][t] = *(const bf16x8*)(slice + (t * 16 + c16) * QK_ROW_B + hh * 64 + g4 * 16);
      kf[hh][t] = *(const bf16x8*)(slice + (t * 16 + c16) * QK_ROW_B + 128 + hh * 64 + g4 * 16);
    }
  asm volatile("s_waitcnt lgkmcnt(0)" ::: "memory");
  __builtin_amdgcn_sched_barrier(0x20);

  f32x4 pacc[2][4][2];
  char* Pb0 = slice;
  char* Pb1 = slice + 8192;
  {
    const f32x4 z4 = {0.f, 0.f, 0.f, 0.f};
    f32x4 dacc[2][4][4];
    __builtin_amdgcn_s_setprio(1);
#pragma unroll
    for (int hh = 0; hh < 2; ++hh)
#pragma unroll
      for (int mt = 0; mt < 4; ++mt)
#pragma unroll
        for (int nt = 0; nt < 4; ++nt)
          dacc[hh][mt][nt] = __builtin_amdgcn_mfma_f32_16x16x32_bf16(qf[hh][mt], kf[hh][nt], z4, 0, 0, 0);
    __builtin_amdgcn_s_setprio(0);

    const int h0 = wave * 2;
#pragma unroll
    for (int mt = 0; mt < 4; ++mt) {
#pragma unroll
      for (int r = 0; r < 4; ++r) {
        const int i = mt * 16 + g4 * 4 + r;
        float p0[4], p1[4], s0 = 0.f, s1 = 0.f;
#pragma unroll
        for (int nt = 0; nt < 4; ++nt) {
          const int j = nt * 16 + c16;
          float v0 = dacc[0][mt][nt][r] * SCALE_F;
          float v1 = dacc[1][mt][nt][r] * SCALE_F;
          if (j < NPOS) {
            if (i < NPOS) { const float bb = bias_s[i * 49 + j]; v0 += bb; v1 += bb; }
          } else {
            v0 = -1e30f; v1 = -1e30f;
          }
          p0[nt] = __expf(v0); s0 += p0[nt];
          p1[nt] = __expf(v1); s1 += p1[nt];
        }
        s0 += __shfl_xor(s0, 1); s1 += __shfl_xor(s1, 1);
        s0 += __shfl_xor(s0, 2); s1 += __shfl_xor(s1, 2);
        s0 += __shfl_xor(s0, 4); s1 += __shfl_xor(s1, 4);
        s0 += __shfl_xor(s0, 8); s1 += __shfl_xor(s1, 8);
        const float inv0 = 1.f / s0, inv1 = 1.f / s1;
        if (i < NPOS) {
          float* ap0 = attng + ((size_t)(work * NHEADS + h0) * 49 + i) * 49;
          float* ap1 = ap0 + 49 * 49;
#pragma unroll
          for (int nt = 0; nt < 4; ++nt) {
            const int j = nt * 16 + c16;
            if (j < NPOS) { ap0[j] = p0[nt] * inv0; ap1[j] = p1[nt] * inv1; }
          }
        }
#pragma unroll
        for (int nt = 0; nt < 4; ++nt) {
          const int j = nt * 16 + c16;
          *(__bf16*)(Pb0 + i * 128 + 16 * ((j >> 3) ^ (i & 7)) + 2 * (j & 7)) = (__bf16)(p0[nt] * inv0);
          *(__bf16*)(Pb1 + i * 128 + 16 * ((j >> 3) ^ (i & 7)) + 2 * (j & 7)) = (__bf16)(p1[nt] * inv1);
        }
      }
    }

    __builtin_amdgcn_s_setprio(1);
#pragma unroll
    for (int hh = 0; hh < 2; ++hh) {
      char* Pb = hh ? Pb1 : Pb0;
#pragma unroll
      for (int mt = 0; mt < 4; ++mt) {
        const int i = mt * 16 + c16;
        bf16x8 pa0 = *(const bf16x8*)(Pb + i * 128 + 16 * ((0 + g4) ^ (i & 7)));
        bf16x8 pa1 = *(const bf16x8*)(Pb + i * 128 + 16 * ((4 + g4) ^ (i & 7)));
#pragma unroll
        for (int nt = 0; nt < 2; ++nt) {
          f32x4 acc = {0.f, 0.f, 0.f, 0.f};
          acc = __builtin_amdgcn_mfma_f32_16x16x32_bf16(pa0, vf[hh][nt][0], acc, 0, 0, 0);
          acc = __builtin_amdgcn_mfma_f32_16x16x32_bf16(pa1, vf[hh][nt][1], acc, 0, 0, 0);
          pacc[hh][mt][nt] = acc;
        }
      }
    }
    __builtin_amdgcn_s_setprio(0);
  }

  if constexpr (MODE == 1) {
    __bf16* ag = aoT_g + (size_t)work * 12544;
#pragma unroll
    for (int hh = 0; hh < 2; ++hh) {
      const int h = wave * 2 + hh;
#pragma unroll
      for (int mt = 0; mt < 4; ++mt)
#pragma unroll
        for (int e = 0; e < 4; ++e) {
          const int pos = mt * 16 + g4 * 4 + e;
          if (pos < NPOS) {
            ag[pos * 256 + h * 32 + c16]      = (__bf16)pacc[hh][mt][0][e];
            ag[pos * 256 + h * 32 + 16 + c16] = (__bf16)pacc[hh][mt][1][e];
          }
        }
    }
  } else {
    __syncthreads();
#pragma unroll
    for (int hh = 0; hh < 2; ++hh) {
      const int h = wave * 2 + hh;
#pragma unroll
      for (int mt = 0; mt < 4; ++mt)
#pragma unroll
        for (int nt = 0; nt < 2; ++nt)
#pragma unroll
          for (int e = 0; e < 4; ++e) {
            const int i = mt * 16 + g4 * 4 + e;
            const int cc = h * 32 + nt * 16 + c16;
            aoT[i * AOT_PITCH + cc] = (__bf16)pacc[hh][mt][nt][e];
          }
    }
    __syncthreads();
    {
      bf16x8 Cf0[16], Cf1[16];
      const __bf16* Bp = aoT + l31 * AOT_PITCH + g2 * 8;
#pragma unroll
      for (int ks = 0; ks < 16; ++ks) {
        Cf0[ks] = *(const bf16x8*)(Bp + ks * 16);
        Cf1[ks] = *(const bf16x8*)(Bp + 32 * AOT_PITCH + ks * 16);
      }
      const __bf16* Ap0 = wo + (size_t)(wave * 64 + l31) * 256 + g2 * 8;
      const __bf16* Ap1 = Ap0 + 32 * 256;
      f32x16 a00 = zero16(), a01 = zero16(), a10 = zero16(), a11 = zero16();
      __builtin_amdgcn_s_setprio(1);
#pragma unroll
      for (int ks = 0; ks < 16; ++ks) {
        bf16x8 A0 = *(const bf16x8*)(Ap0 + ks * 16);
        bf16x8 A1 = *(const bf16x8*)(Ap1 + ks * 16);
        a00 = __builtin_amdgcn_mfma_f32_32x32x16_bf16(A0, Cf0[ks], a00, 0, 0, 0);
        a01 = __builtin_amdgcn_mfma_f32_32x32x16_bf16(A0, Cf1[ks], a01, 0, 0, 0);
        a10 = __builtin_amdgcn_mfma_f32_32x32x16_bf16(A1, Cf0[ks], a10, 0, 0, 0);
        a11 = __builtin_amdgcn_mfma_f32_32x32x16_bf16(A1, Cf1[ks], a11, 0, 0, 0);
      }
      __builtin_amdgcn_s_setprio(0);
      float* og = outg + (size_t)b * 256 * 12544;
#define STORE_OUT(ACC, MT, NT)                                                    \
      {                                                                           \
        const int n_ = (NT) * 32 + l31;                                           \
        if (n_ < NPOS) {                                                          \
          const int pr_ = n_ / 7, pc_ = n_ - pr_ * 7;                             \
          float* orow = og + (size_t)(r0 + pr_) * 112 + (c0 + pc_);               \
          _Pragma("unroll") for (int rg = 0; rg < 16; ++rg) {                     \
            const int o2 = wave * 64 + (MT) * 32 + (rg & 3) + 8 * (rg >> 2) + 4 * g2; \
            orow[(size_t)o2 * 12544] = ACC[rg] + bo_s[o2];                        \
          }                                                                       \
        }                                                                         \
      }
      STORE_OUT(a00, 0, 0)
      STORE_OUT(a01, 0, 1)
      STORE_OUT(a10, 1, 0)
      STORE_OUT(a11, 1, 1)
    }
  }
}

// ---------------- oproj: out[b][oc][row][0..111] = Wo @ attn_out + bo ----------------
__global__ __launch_bounds__(256, 2) void oproj_kernel(
    const __bf16* __restrict__ aoT_g, const __bf16* __restrict__ wo,
    const float* __restrict__ bo_g, float* __restrict__ outg) {
  __shared__ __bf16 aoB[112 * 264];
  __shared__ float bo_s[256];
  const int tid = threadIdx.x;
  const int bid = blockIdx.x;
  const int work = (bid & 7) * 224 + (bid >> 3);
  const int pr = work % 7;
  const int g  = work / 7;
  const int i1 = g & 15, b = g >> 4;
  const int wave = tid >> 6, lane = tid & 63;
  const int c16 = lane & 15, g4 = lane >> 4;

  {
    const int rr = tid >> 5, coff = (tid & 31) * 8;
#pragma unroll
    for (int it = 0; it < 14; ++it) {
      const int gr = it * 8 + rr;
      const int i2 = gr / 7, pc = gr - i2 * 7;
      const size_t src = ((size_t)((b * 256 + i1 * 16 + i2) * 49 + pr * 7 + pc)) * 256 + coff;
      *(bf16x8*)(aoB + gr * 264 + coff) = *(const bf16x8*)(aoT_g + src);
    }
    bo_s[tid] = bo_g[tid];
  }
  __syncthreads();

  const int oc0 = wave * 64;
  f32x4 acc[4][7];
#pragma unroll
  for (int mt = 0; mt < 4; ++mt)
#pragma unroll
    for (int nt = 0; nt < 7; ++nt) acc[mt][nt] = f32x4{0.f, 0.f, 0.f, 0.f};
#pragma unroll
  for (int kk = 0; kk < 8; ++kk) {
    bf16x8 Af[4], Bf[7];
#pragma unroll
    for (int mt = 0; mt < 4; ++mt)
      Af[mt] = *(const bf16x8*)(wo + (size_t)(oc0 + mt * 16 + c16) * 256 + kk * 32 + g4 * 8);
#pragma unroll
    for (int nt = 0; nt < 7; ++nt)
      Bf[nt] = *(const bf16x8*)(aoB + (nt * 16 + c16) * 264 + kk * 32 + g4 * 8);
    __builtin_amdgcn_s_setprio(1);
#pragma unroll
    for (int mt = 0; mt < 4; ++mt)
#pragma unroll
      for (int nt = 0; nt < 7; ++nt)
        acc[mt][nt] = __builtin_amdgcn_mfma_f32_16x16x32_bf16(Af[mt], Bf[nt], acc[mt][nt], 0, 0, 0);
    __builtin_amdgcn_s_setprio(0);
  }
  float* orow = outg + (size_t)b * 256 * 12544 + (size_t)(i1 * 7 + pr) * 112;
#pragma unroll
  for (int mt = 0; mt < 4; ++mt)
#pragma unroll
    for (int e = 0; e < 4; ++e) {
      const int oc = oc0 + mt * 16 + g4 * 4 + e;
      const float bb = bo_s[oc];
#pragma unroll
      for (int nt = 0; nt < 7; ++nt)
        orow[(size_t)oc * 12544 + nt * 16 + c16] = acc[mt][nt][e] + bb;
    }
}

extern "C" void kernel_launch(void* const* d_in, const int* in_sizes, int n_in,
                              void* d_out, int out_size, void* d_ws, size_t ws_size,
                              hipStream_t stream) {
  const float* x   = (const float*)d_in[0];
  const float* Wq  = (const float*)d_in[1];
  const float* Wkv = (const float*)d_in[2];
  const float* Wo  = (const float*)d_in[3];
  const float* bo  = (const float*)d_in[4];
  const float* pos = (const float*)d_in[5];
  const int*   rel = (const int*)d_in[6];

  float* outg  = (float*)d_out;
  float* attng = outg + (size_t)16 * 256 * 112 * 112;

  __bf16* wqkv = (__bf16*)d_ws;
  __bf16* wo   = wqkv + 768 * 256;
  float*  bias = (float*)(wo + 256 * 256);

  size_t base = 768 * 256 * 2 + 256 * 256 * 2 + 2401 * 4;
  base = (base + 255) & ~(size_t)255;
  const size_t ao_bytes = (size_t)4096 * 12544 * 2;
  const size_t qk_bytes = (size_t)4096 * 8 * 3136;   // q or k: [win][h][49][32] bf16
  const size_t vt_bytes = (size_t)4096 * 8 * 4096;   // vT: [win][h][32][64] bf16
  const size_t q_off = base + ao_bytes;
  const size_t k_off = q_off + qk_bytes;
  const size_t v_off = k_off + qk_bytes;
  const size_t full  = v_off + vt_bytes;

  __bf16* aoT_g = (__bf16*)((char*)d_ws + base);
  __bf16* qg    = (__bf16*)((char*)d_ws + q_off);
  __bf16* kg    = (__bf16*)((char*)d_ws + k_off);
  __bf16* vtg   = (__bf16*)((char*)d_ws + v_off);

  hipFuncSetAttribute((const void*)attn_kernel<0>,
                      hipFuncAttributeMaxDynamicSharedMemorySize, LDS_BYTES);
  hipFuncSetAttribute((const void*)attn_kernel<1>,
                      hipFuncAttributeMaxDynamicSharedMemorySize, LDS_BYTES);
  hipFuncSetAttribute((const void*)qkv_kernel,
                      hipFuncAttributeMaxDynamicSharedMemorySize, QKV_LDS);
  hipFuncSetAttribute((const void*)att_kernel,
                      hipFuncAttributeMaxDynamicSharedMemorySize, ATT_LDS);

  prep_kernel<<<dim3(512), dim3(256), 0, stream>>>(Wq, Wkv, Wo, pos, rel, wqkv, wo, bias);
  if (ws_size >= full) {
    qkv_kernel<<<dim3(4096), dim3(256), QKV_LDS, stream>>>(x, wqkv, qg, kg, vtg);
    att_kernel<<<dim3(8192), dim3(256), ATT_LDS, stream>>>(qg, kg, vtg, bias, attng, aoT_g);
    oproj_kernel<<<dim3(1792), dim3(256), 0, stream>>>(aoT_g, wo, bo, outg);
  } else if (ws_size >= base + ao_bytes) {
    attn_kernel<1><<<dim3(4096), dim3(256), LDS_BYTES, stream>>>(
        x, wqkv, wo, bias, bo, outg, attng, aoT_g);
    oproj_kernel<<<dim3(1792), dim3(256), 0, stream>>>(aoT_g, wo, bo, outg);
  } else {
    attn_kernel<0><<<dim3(4096), dim3(256), LDS_BYTES, stream>>>(
        x, wqkv, wo, bias, bo, outg, attng, nullptr);
  }
}

// Round 8
// 521.742 us; speedup vs baseline: 1.1598x; 1.1019x over previous
//
#include <hip/hip_runtime.h>
#include <hip/hip_bf16.h>

typedef __bf16 bf16x8 __attribute__((ext_vector_type(8)));
typedef __bf16 bf16x4 __attribute__((ext_vector_type(4)));
typedef float  f32x4  __attribute__((ext_vector_type(4)));
typedef float  f32x16 __attribute__((ext_vector_type(16)));
typedef float  f32x4a __attribute__((ext_vector_type(4))) __attribute__((aligned(4)));
typedef float  f32x2a __attribute__((ext_vector_type(2))) __attribute__((aligned(4)));

#define NPOS 49
#define NHEADS 8
#define SCALE_F 0.17677669529663687f

// ---- legacy (round-5) LDS layout ----
#define SLICE_B   16896
#define QK_ROW_B  264
#define VS_OFF    8192
#define VS_ROW_B  136
#define XWT_PITCH 264
#define AOT_PITCH 264
#define BIAS_OFF  67584
#define BO_OFF    77188
#define LDS_BYTES 78212

// ---- qkv kernel ----
#define XW2_PITCH 268                    // elements; 536 B rows -> 2-way-max LDS banking
#define QKV_LDS   (64 * XW2_PITCH * 2)   // 34304 B
#define ATT_LDS   (4 * 8192)             // 32768 B (4 P-buffers)

static __device__ __forceinline__ f32x16 zero16() {
  f32x16 z;
#pragma unroll
  for (int i = 0; i < 16; ++i) z[i] = 0.f;
  return z;
}

// prep: bf16 weight copies (legacy) + MFMA-fragment-packed copies (fast path)
// wqkvP[((s*16+ks)*64 + lane)*8 + e] = W[s*32 + (lane&31)][ks*16 + (lane>>5)*8 + e]
// woP  [((t*8+kk)*64 + lane)*8 + e]  = Wo[t*16 + (lane&15)][kk*32 + (lane>>4)*8 + e]
__global__ void prep_kernel(const float* __restrict__ Wq, const float* __restrict__ Wkv,
                            const float* __restrict__ Wo, const float* __restrict__ pos,
                            const int* __restrict__ rel, __bf16* __restrict__ wqkv,
                            __bf16* __restrict__ wo, float* __restrict__ bias,
                            __bf16* __restrict__ wqkvP, __bf16* __restrict__ woP) {
  const int idx = blockIdx.x * 256 + threadIdx.x;   // 0 .. 768*256-1
  const int row = idx >> 8, col = idx & 255;
  const float wv = (row < 256) ? Wq[idx] : Wkv[idx - 65536];
  wqkv[idx] = (__bf16)wv;
  {
    const int s = row >> 5, l31 = row & 31;
    const int ks = col >> 4, g2 = (col >> 3) & 1, e = col & 7;
    wqkvP[((size_t)((s * 16 + ks) * 64 + g2 * 32 + l31)) * 8 + e] = (__bf16)wv;
  }
  if (idx < 65536) {
    const float w = Wo[idx];
    wo[idx] = (__bf16)w;
    const int t = row >> 4, c16 = row & 15;
    const int kk = col >> 5, g4 = (col >> 3) & 3, e = col & 7;
    woP[((size_t)((t * 8 + kk) * 64 + g4 * 16 + c16)) * 8 + e] = (__bf16)w;
  }
  if (idx < 49 * 49) bias[idx] = pos[rel[idx * 2] * 13 + rel[idx * 2 + 1]];
}

// =====================================================================
// kernel 1: qkv projection. One block per window, 4 waves.
// A-fragments from packed wqkvP: 64 lanes x 16B contiguous per load.
// =====================================================================
__global__ __launch_bounds__(256, 4) void qkv_kernel(
    const float* __restrict__ x, const __bf16* __restrict__ wqkvP,
    __bf16* __restrict__ qg, __bf16* __restrict__ kg, __bf16* __restrict__ vtg) {
  extern __shared__ char smem[];
  __bf16* xwT = (__bf16*)smem;

  const int tid = threadIdx.x;
  const int bid = blockIdx.x;
  const int work = (bid & 7) * 512 + (bid >> 3);  // XCD swizzle
  const int b  = work >> 8;
  const int i1 = (work >> 4) & 15;
  const int i2 = work & 15;
  const int r0 = i1 * 7, c0 = i2 * 7;
  const int wave = tid >> 6, lane = tid & 63;
  const int l31 = lane & 31, g2 = lane >> 5;

  // zero-fill pad rows 49..63
  {
    bf16x8 z8;
#pragma unroll
    for (int j = 0; j < 8; ++j) z8[j] = (__bf16)0.f;
    for (int i = tid; i < 480; i += 256) {
      const int row = 49 + (i >> 5);
      const int col = (i & 31) * 8;
      *(bf16x8*)(xwT + row * XW2_PITCH + col) = z8;
    }
  }

  // gather x window: 1792 (ch,row) pairs; 7 per thread; wide loads
  {
    f32x4a b4[7]; f32x2a b2[7]; float b1[7];
    int chv[7], rowv[7];
    const float* xb = x + (size_t)b * 256 * 12544;
#pragma unroll
    for (int k = 0; k < 7; ++k) {
      const int p = k * 256 + tid;
      const int ch = p / 7;
      const int row = p - ch * 7;
      chv[k] = ch; rowv[k] = row;
      const float* xr = xb + (size_t)ch * 12544 + (size_t)(r0 + row) * 112 + c0;
      b4[k] = *(const f32x4a*)xr;
      b2[k] = *(const f32x2a*)(xr + 4);
      b1[k] = xr[6];
    }
#pragma unroll
    for (int k = 0; k < 7; ++k) {
      __bf16* dst = xwT + (rowv[k] * 7) * XW2_PITCH + chv[k];
      dst[0 * XW2_PITCH] = (__bf16)b4[k][0];
      dst[1 * XW2_PITCH] = (__bf16)b4[k][1];
      dst[2 * XW2_PITCH] = (__bf16)b4[k][2];
      dst[3 * XW2_PITCH] = (__bf16)b4[k][3];
      dst[4 * XW2_PITCH] = (__bf16)b2[k][0];
      dst[5 * XW2_PITCH] = (__bf16)b2[k][1];
      dst[6 * XW2_PITCH] = (__bf16)b1[k];
    }
  }
  __syncthreads();

  const size_t hb = (size_t)work * 8;

#pragma unroll
  for (int p = 3 * wave; p < 3 * wave + 3; ++p) {
    // packed strips 2p, 2p+1; per strip: 16 ks x 512 elements
    const __bf16* A0p = wqkvP + (size_t)(2 * p) * 8192 + lane * 8;
    const __bf16* A1p = A0p + 8192;
    const __bf16* Bp  = xwT + l31 * XW2_PITCH + g2 * 8;
    f32x16 a00 = zero16(), a01 = zero16(), a10 = zero16(), a11 = zero16();
    __builtin_amdgcn_s_setprio(1);
#pragma unroll
    for (int ks = 0; ks < 16; ++ks) {
      bf16x8 B0 = *(const bf16x8*)(Bp + ks * 16);
      bf16x8 B1 = *(const bf16x8*)(Bp + 32 * XW2_PITCH + ks * 16);
      bf16x8 A0 = *(const bf16x8*)(A0p + ks * 512);
      bf16x8 A1 = *(const bf16x8*)(A1p + ks * 512);
      a00 = __builtin_amdgcn_mfma_f32_32x32x16_bf16(A0, B0, a00, 0, 0, 0);
      a01 = __builtin_amdgcn_mfma_f32_32x32x16_bf16(A0, B1, a01, 0, 0, 0);
      a10 = __builtin_amdgcn_mfma_f32_32x32x16_bf16(A1, B0, a10, 0, 0, 0);
      a11 = __builtin_amdgcn_mfma_f32_32x32x16_bf16(A1, B1, a11, 0, 0, 0);
    }
    __builtin_amdgcn_s_setprio(0);
#define QKV_STORE(ACC, S, NT)                                                  \
    {                                                                          \
      const int sec = (S) >> 3, h = (S) & 7;                                   \
      const int n_ = (NT) * 32 + l31;                                          \
      if (sec < 2) {                                                           \
        if (n_ < NPOS) {                                                       \
          __bf16* bp = (sec ? kg : qg) + (hb + h) * 1568 + n_ * 32;            \
          _Pragma("unroll") for (int rb = 0; rb < 4; ++rb) {                   \
            bf16x4 v4;                                                         \
            v4[0] = (__bf16)ACC[rb * 4 + 0]; v4[1] = (__bf16)ACC[rb * 4 + 1];  \
            v4[2] = (__bf16)ACC[rb * 4 + 2]; v4[3] = (__bf16)ACC[rb * 4 + 3];  \
            *(bf16x4*)(bp + 8 * rb + 4 * g2) = v4;                             \
          }                                                                    \
        }                                                                      \
      } else {                                                                 \
        __bf16* vp = vtg + (hb + h) * 2048 + n_;                               \
        _Pragma("unroll") for (int rg = 0; rg < 16; ++rg) {                    \
          const int dd = (rg & 3) + 8 * (rg >> 2) + 4 * g2;                    \
          vp[dd * 64] = (__bf16)ACC[rg];                                       \
        }                                                                      \
      }                                                                        \
    }
    QKV_STORE(a00, 2 * p, 0)
    QKV_STORE(a01, 2 * p, 1)
    QKV_STORE(a10, 2 * p + 1, 0)
    QKV_STORE(a11, 2 * p + 1, 1)
  }
}

// =====================================================================
// kernel 2: attention. One wave per (window, head); 4 waves/block;
// no __syncthreads. P lives in an 8 KB per-wave LDS buffer.
// =====================================================================
__global__ __launch_bounds__(256, 3) void att_kernel(
    const __bf16* __restrict__ qg, const __bf16* __restrict__ kg,
    const __bf16* __restrict__ vtg, const float* __restrict__ bias_g,
    float* __restrict__ attng, __bf16* __restrict__ aoT_g) {
  extern __shared__ char smem[];
  const int tid = threadIdx.x;
  const int bid = blockIdx.x;
  const int work = (bid & 7) * 1024 + (bid >> 3);  // XCD swizzle, 8192 blocks
  const int win  = work >> 1;
  const int wave = tid >> 6, lane = tid & 63;
  const int head = (work & 1) * 4 + wave;
  const int c16 = lane & 15, g4 = lane >> 4;
  char* Pb = smem + wave * 8192;

  const size_t hidx = (size_t)win * 8 + head;
  const __bf16* qb = qg + hidx * 1568;
  const __bf16* kb = kg + hidx * 1568;
  const __bf16* vb = vtg + hidx * 2048;

  bf16x8 qf[4], kf[4];
#pragma unroll
  for (int t = 0; t < 4; ++t) {
    int rr = t * 16 + c16; rr = rr > 48 ? 48 : rr;
    qf[t] = *(const bf16x8*)(qb + rr * 32 + g4 * 8);
    kf[t] = *(const bf16x8*)(kb + rr * 32 + g4 * 8);
  }
  bf16x8 vf[2][2];
#pragma unroll
  for (int nt = 0; nt < 2; ++nt)
#pragma unroll
    for (int ks = 0; ks < 2; ++ks)
      vf[nt][ks] = *(const bf16x8*)(vb + (nt * 16 + c16) * 64 + ks * 32 + g4 * 8);

  f32x4 dacc[4][4];
  const f32x4 z4 = {0.f, 0.f, 0.f, 0.f};
  __builtin_amdgcn_s_setprio(1);
#pragma unroll
  for (int mt = 0; mt < 4; ++mt)
#pragma unroll
    for (int nt = 0; nt < 4; ++nt)
      dacc[mt][nt] = __builtin_amdgcn_mfma_f32_16x16x32_bf16(qf[mt], kf[nt], z4, 0, 0, 0);
  __builtin_amdgcn_s_setprio(0);

  // softmax (no max-subtraction: scores are O(1); identical to reference math)
#pragma unroll
  for (int mt = 0; mt < 4; ++mt) {
#pragma unroll
    for (int r = 0; r < 4; ++r) {
      const int i = mt * 16 + g4 * 4 + r;
      float p[4], s = 0.f;
#pragma unroll
      for (int nt = 0; nt < 4; ++nt) {
        const int j = nt * 16 + c16;
        float val = dacc[mt][nt][r] * SCALE_F;
        if (j < NPOS) {
          if (i < NPOS) val += bias_g[i * 49 + j];
        } else {
          val = -1e30f;
        }
        p[nt] = __expf(val); s += p[nt];
      }
      s += __shfl_xor(s, 1); s += __shfl_xor(s, 2);
      s += __shfl_xor(s, 4); s += __shfl_xor(s, 8);
      const float inv = 1.f / s;
      if (i < NPOS) {
        float* ap = attng + ((size_t)(win * NHEADS + head) * 49 + i) * 49;
#pragma unroll
        for (int nt = 0; nt < 4; ++nt) {
          const int j = nt * 16 + c16;
          if (j < NPOS) ap[j] = p[nt] * inv;
        }
      }
#pragma unroll
      for (int nt = 0; nt < 4; ++nt) {
        const int j = nt * 16 + c16;
        *(__bf16*)(Pb + i * 128 + 16 * ((j >> 3) ^ (i & 7)) + 2 * (j & 7)) = (__bf16)(p[nt] * inv);
      }
    }
  }

  // PV
  f32x4 pacc[4][2];
  __builtin_amdgcn_s_setprio(1);
#pragma unroll
  for (int mt = 0; mt < 4; ++mt) {
    const int i = mt * 16 + c16;
    bf16x8 pa0 = *(const bf16x8*)(Pb + i * 128 + 16 * ((0 + g4) ^ (i & 7)));
    bf16x8 pa1 = *(const bf16x8*)(Pb + i * 128 + 16 * ((4 + g4) ^ (i & 7)));
#pragma unroll
    for (int nt = 0; nt < 2; ++nt) {
      f32x4 acc = {0.f, 0.f, 0.f, 0.f};
      acc = __builtin_amdgcn_mfma_f32_16x16x32_bf16(pa0, vf[nt][0], acc, 0, 0, 0);
      acc = __builtin_amdgcn_mfma_f32_16x16x32_bf16(pa1, vf[nt][1], acc, 0, 0, 0);
      pacc[mt][nt] = acc;
    }
  }
  __builtin_amdgcn_s_setprio(0);

  __bf16* ag = aoT_g + (size_t)win * 12544;
#pragma unroll
  for (int mt = 0; mt < 4; ++mt)
#pragma unroll
    for (int e = 0; e < 4; ++e) {
      const int pos = mt * 16 + g4 * 4 + e;
      if (pos < NPOS) {
        ag[pos * 256 + head * 32 + c16]      = (__bf16)pacc[mt][0][e];
        ag[pos * 256 + head * 32 + 16 + c16] = (__bf16)pacc[mt][1][e];
      }
    }
}

// =====================================================================
// LEGACY fallback (round-5): monolithic / split attn kernel (unpacked weights)
// =====================================================================
template <int MODE>
__global__ __launch_bounds__(256, 2) void attn_kernel(
    const float* __restrict__ x, const __bf16* __restrict__ wqkv,
    const __bf16* __restrict__ wo, const float* __restrict__ bias_g,
    const float* __restrict__ bo_g, float* __restrict__ outg,
    float* __restrict__ attng, __bf16* __restrict__ aoT_g) {
  extern __shared__ char smem[];
  __bf16* xwT = (__bf16*)smem;
  __bf16* aoT = (__bf16*)smem;
  float* bias_s = (float*)(smem + BIAS_OFF);
  float* bo_s   = (float*)(smem + BO_OFF);

  const int tid = threadIdx.x;
  const int bid = blockIdx.x;
  const int work = (bid & 7) * 512 + (bid >> 3);
  const int b  = work >> 8;
  const int i1 = (work >> 4) & 15;
  const int i2 = work & 15;
  const int r0 = i1 * 7, c0 = i2 * 7;
  const int wave = tid >> 6, lane = tid & 63;
  const int l31 = lane & 31, g2 = lane >> 5;
  const int c16 = lane & 15, g4 = lane >> 4;
  char* slice = smem + wave * SLICE_B;

  {
    const int n = tid & 63, cb = tid >> 6;
    const int np = (n < NPOS) ? n : 0;
    const float zf = (n < NPOS) ? 1.f : 0.f;
    const int pr = np / 7, pc = np - pr * 7;
    const float* xg = x + (size_t)b * 256 * 12544 + (size_t)(r0 + pr) * 112 + (c0 + pc);
    float tmp[64];
#pragma unroll
    for (int it = 0; it < 64; ++it)
      tmp[it] = xg[(size_t)(it * 4 + cb) * 12544];
#pragma unroll
    for (int it = 0; it < 64; ++it)
      xwT[n * XWT_PITCH + it * 4 + cb] = (__bf16)(tmp[it] * zf);
    const float4* bg4 = (const float4*)bias_g;
    for (int i = tid; i < 600; i += 256) ((float4*)bias_s)[i] = bg4[i];
    if (tid == 0) bias_s[2400] = bias_g[2400];
    if constexpr (MODE == 0) bo_s[tid] = bo_g[tid];
  }
  __syncthreads();

  bf16x8 Bf0[16], Bf1[16];
  {
    const __bf16* Bp = xwT + l31 * XWT_PITCH + g2 * 8;
#pragma unroll
    for (int ks = 0; ks < 16; ++ks) {
      Bf0[ks] = *(const bf16x8*)(Bp + ks * 16);
      Bf1[ks] = *(const bf16x8*)(Bp + 32 * XWT_PITCH + ks * 16);
    }
  }
  __syncthreads();

  char* vsb = slice + VS_OFF;
  {
    const __bf16* Ap0 = wqkv + (size_t)(512 + 64 * wave + l31) * 256 + g2 * 8;
    const __bf16* Ap1 = Ap0 + 32 * 256;
    f32x16 a00 = zero16(), a01 = zero16(), a10 = zero16(), a11 = zero16();
    __builtin_amdgcn_s_setprio(1);
#pragma unroll
    for (int ks = 0; ks < 16; ++ks) {
      bf16x8 A0 = *(const bf16x8*)(Ap0 + ks * 16);
      bf16x8 A1 = *(const bf16x8*)(Ap1 + ks * 16);
      a00 = __builtin_amdgcn_mfma_f32_32x32x16_bf16(A0, Bf0[ks], a00, 0, 0, 0);
      a01 = __builtin_amdgcn_mfma_f32_32x32x16_bf16(A0, Bf1[ks], a01, 0, 0, 0);
      a10 = __builtin_amdgcn_mfma_f32_32x32x16_bf16(A1, Bf0[ks], a10, 0, 0, 0);
      a11 = __builtin_amdgcn_mfma_f32_32x32x16_bf16(A1, Bf1[ks], a11, 0, 0, 0);
    }
    __builtin_amdgcn_s_setprio(0);
#pragma unroll
    for (int rg = 0; rg < 16; ++rg) {
      const int dd = (rg & 3) + 8 * (rg >> 2) + 4 * g2;
      *(__bf16*)(vsb + dd * VS_ROW_B + l31 * 2)              = (__bf16)a00[rg];
      *(__bf16*)(vsb + dd * VS_ROW_B + 64 + l31 * 2)         = (__bf16)a01[rg];
      *(__bf16*)(vsb + (32 + dd) * VS_ROW_B + l31 * 2)       = (__bf16)a10[rg];
      *(__bf16*)(vsb + (32 + dd) * VS_ROW_B + 64 + l31 * 2)  = (__bf16)a11[rg];
    }
  }
  bf16x8 vf[2][2][2];
#pragma unroll
  for (int hh = 0; hh < 2; ++hh)
#pragma unroll
    for (int nt = 0; nt < 2; ++nt)
#pragma unroll
      for (int ks = 0; ks < 2; ++ks)
        vf[hh][nt][ks] = *(const bf16x8*)(vsb + (hh * 32 + nt * 16 + c16) * VS_ROW_B + ks * 64 + g4 * 16);
  asm volatile("s_waitcnt lgkmcnt(0)" ::: "memory");
  __builtin_amdgcn_sched_barrier(0x20);

#pragma unroll
  for (int qk = 0; qk < 2; ++qk) {
    const int rowbase = qk * 256 + 64 * wave;
    const int koff = qk * 64;
    const __bf16* Ap0 = wqkv + (size_t)(rowbase + l31) * 256 + g2 * 8;
    const __bf16* Ap1 = Ap0 + 32 * 256;
    f32x16 a00 = zero16(), a01 = zero16(), a10 = zero16(), a11 = zero16();
    __builtin_amdgcn_s_setprio(1);
#pragma unroll
    for (int ks = 0; ks < 16; ++ks) {
      bf16x8 A0 = *(const bf16x8*)(Ap0 + ks * 16);
      bf16x8 A1 = *(const bf16x8*)(Ap1 + ks * 16);
      a00 = __builtin_amdgcn_mfma_f32_32x32x16_bf16(A0, Bf0[ks], a00, 0, 0, 0);
      a01 = __builtin_amdgcn_mfma_f32_32x32x16_bf16(A0, Bf1[ks], a01, 0, 0, 0);
      a10 = __builtin_amdgcn_mfma_f32_32x32x16_bf16(A1, Bf0[ks], a10, 0, 0, 0);
      a11 = __builtin_amdgcn_mfma_f32_32x32x16_bf16(A1, Bf1[ks], a11, 0, 0, 0);
    }
    __builtin_amdgcn_s_setprio(0);
#define STORE_QK(ACC, P_, NT)                                                  \
    {                                                                          \
      const int n_ = (NT) * 32 + l31;                                          \
      _Pragma("unroll") for (int rb = 0; rb < 4; ++rb) {                       \
        const int ddb = koff + (P_) * 32 + rb * 8 + g2 * 4;                    \
        bf16x4 v4;                                                             \
        v4[0] = (__bf16)ACC[rb * 4 + 0]; v4[1] = (__bf16)ACC[rb * 4 + 1];      \
        v4[2] = (__bf16)ACC[rb * 4 + 2]; v4[3] = (__bf16)ACC[rb * 4 + 3];      \
        *(bf16x4*)(slice + n_ * QK_ROW_B + ddb * 2) = v4;                      \
      }                                                                        \
    }
    STORE_QK(a00, 0, 0)
    STORE_QK(a01, 0, 1)
    STORE_QK(a10, 1, 0)
    STORE_QK(a11, 1, 1)
  }
  bf16x8 qf[2][4], kf[2][4];
#pragma unroll
  for (int hh = 0; hh < 2; ++hh)
#pragma unroll
    for (int t = 0; t < 4; ++t) {
      qf[hh][t] = *(const bf16x8*)(slice + (t * 16 + c16) * QK_ROW_B + hh * 64 + g4 * 16);
      kf[hh][t] = *(const bf16x8*)(slice + (t * 16 + c16) * QK_ROW_B + 128 + hh * 64 + g4 * 16);
    }
  asm volatile("s_waitcnt lgkmcnt(0)" ::: "memory");
  __builtin_amdgcn_sched_barrier(0x20);

  f32x4 pacc[2][4][2];
  char* Pb0 = slice;
  char* Pb1 = slice + 8192;
  {
    const f32x4 z4 = {0.f, 0.f, 0.f, 0.f};
    f32x4 dacc[2][4][4];
    __builtin_amdgcn_s_setprio(1);
#pragma unroll
    for (int hh = 0; hh < 2; ++hh)
#pragma unroll
      for (int mt = 0; mt < 4; ++mt)
#pragma unroll
        for (int nt = 0; nt < 4; ++nt)
          dacc[hh][mt][nt] = __builtin_amdgcn_mfma_f32_16x16x32_bf16(qf[hh][mt], kf[hh][nt], z4, 0, 0, 0);
    __builtin_amdgcn_s_setprio(0);

    const int h0 = wave * 2;
#pragma unroll
    for (int mt = 0; mt < 4; ++mt) {
#pragma unroll
      for (int r = 0; r < 4; ++r) {
        const int i = mt * 16 + g4 * 4 + r;
        float p0[4], p1[4], s0 = 0.f, s1 = 0.f;
#pragma unroll
        for (int nt = 0; nt < 4; ++nt) {
          const int j = nt * 16 + c16;
          float v0 = dacc[0][mt][nt][r] * SCALE_F;
          float v1 = dacc[1][mt][nt][r] * SCALE_F;
          if (j < NPOS) {
            if (i < NPOS) { const float bb = bias_s[i * 49 + j]; v0 += bb; v1 += bb; }
          } else {
            v0 = -1e30f; v1 = -1e30f;
          }
          p0[nt] = __expf(v0); s0 += p0[nt];
          p1[nt] = __expf(v1); s1 += p1[nt];
        }
        s0 += __shfl_xor(s0, 1); s1 += __shfl_xor(s1, 1);
        s0 += __shfl_xor(s0, 2); s1 += __shfl_xor(s1, 2);
        s0 += __shfl_xor(s0, 4); s1 += __shfl_xor(s1, 4);
        s0 += __shfl_xor(s0, 8); s1 += __shfl_xor(s1, 8);
        const float inv0 = 1.f / s0, inv1 = 1.f / s1;
        if (i < NPOS) {
          float* ap0 = attng + ((size_t)(work * NHEADS + h0) * 49 + i) * 49;
          float* ap1 = ap0 + 49 * 49;
#pragma unroll
          for (int nt = 0; nt < 4; ++nt) {
            const int j = nt * 16 + c16;
            if (j < NPOS) { ap0[j] = p0[nt] * inv0; ap1[j] = p1[nt] * inv1; }
          }
        }
#pragma unroll
        for (int nt = 0; nt < 4; ++nt) {
          const int j = nt * 16 + c16;
          *(__bf16*)(Pb0 + i * 128 + 16 * ((j >> 3) ^ (i & 7)) + 2 * (j & 7)) = (__bf16)(p0[nt] * inv0);
          *(__bf16*)(Pb1 + i * 128 + 16 * ((j >> 3) ^ (i & 7)) + 2 * (j & 7)) = (__bf16)(p1[nt] * inv1);
        }
      }
    }

    __builtin_amdgcn_s_setprio(1);
#pragma unroll
    for (int hh = 0; hh < 2; ++hh) {
      char* Pb = hh ? Pb1 : Pb0;
#pragma unroll
      for (int mt = 0; mt < 4; ++mt) {
        const int i = mt * 16 + c16;
        bf16x8 pa0 = *(const bf16x8*)(Pb + i * 128 + 16 * ((0 + g4) ^ (i & 7)));
        bf16x8 pa1 = *(const bf16x8*)(Pb + i * 128 + 16 * ((4 + g4) ^ (i & 7)));
#pragma unroll
        for (int nt = 0; nt < 2; ++nt) {
          f32x4 acc = {0.f, 0.f, 0.f, 0.f};
          acc = __builtin_amdgcn_mfma_f32_16x16x32_bf16(pa0, vf[hh][nt][0], acc, 0, 0, 0);
          acc = __builtin_amdgcn_mfma_f32_16x16x32_bf16(pa1, vf[hh][nt][1], acc, 0, 0, 0);
          pacc[hh][mt][nt] = acc;
        }
      }
    }
    __builtin_amdgcn_s_setprio(0);
  }

  if constexpr (MODE == 1) {
    __bf16* ag = aoT_g + (size_t)work * 12544;
#pragma unroll
    for (int hh = 0; hh < 2; ++hh) {
      const int h = wave * 2 + hh;
#pragma unroll
      for (int mt = 0; mt < 4; ++mt)
#pragma unroll
        for (int e = 0; e < 4; ++e) {
          const int pos = mt * 16 + g4 * 4 + e;
          if (pos < NPOS) {
            ag[pos * 256 + h * 32 + c16]      = (__bf16)pacc[hh][mt][0][e];
            ag[pos * 256 + h * 32 + 16 + c16] = (__bf16)pacc[hh][mt][1][e];
          }
        }
    }
  } else {
    __syncthreads();
#pragma unroll
    for (int hh = 0; hh < 2; ++hh) {
      const int h = wave * 2 + hh;
#pragma unroll
      for (int mt = 0; mt < 4; ++mt)
#pragma unroll
        for (int nt = 0; nt < 2; ++nt)
#pragma unroll
          for (int e = 0; e < 4; ++e) {
            const int i = mt * 16 + g4 * 4 + e;
            const int cc = h * 32 + nt * 16 + c16;
            aoT[i * AOT_PITCH + cc] = (__bf16)pacc[hh][mt][nt][e];
          }
    }
    __syncthreads();
    {
      bf16x8 Cf0[16], Cf1[16];
      const __bf16* Bp = aoT + l31 * AOT_PITCH + g2 * 8;
#pragma unroll
      for (int ks = 0; ks < 16; ++ks) {
        Cf0[ks] = *(const bf16x8*)(Bp + ks * 16);
        Cf1[ks] = *(const bf16x8*)(Bp + 32 * AOT_PITCH + ks * 16);
      }
      const __bf16* Ap0 = wo + (size_t)(wave * 64 + l31) * 256 + g2 * 8;
      const __bf16* Ap1 = Ap0 + 32 * 256;
      f32x16 a00 = zero16(), a01 = zero16(), a10 = zero16(), a11 = zero16();
      __builtin_amdgcn_s_setprio(1);
#pragma unroll
      for (int ks = 0; ks < 16; ++ks) {
        bf16x8 A0 = *(const bf16x8*)(Ap0 + ks * 16);
        bf16x8 A1 = *(const bf16x8*)(Ap1 + ks * 16);
        a00 = __builtin_amdgcn_mfma_f32_32x32x16_bf16(A0, Cf0[ks], a00, 0, 0, 0);
        a01 = __builtin_amdgcn_mfma_f32_32x32x16_bf16(A0, Cf1[ks], a01, 0, 0, 0);
        a10 = __builtin_amdgcn_mfma_f32_32x32x16_bf16(A1, Cf0[ks], a10, 0, 0, 0);
        a11 = __builtin_amdgcn_mfma_f32_32x32x16_bf16(A1, Cf1[ks], a11, 0, 0, 0);
      }
      __builtin_amdgcn_s_setprio(0);
      float* og = outg + (size_t)b * 256 * 12544;
#define STORE_OUT(ACC, MT, NT)                                                    \
      {                                                                           \
        const int n_ = (NT) * 32 + l31;                                           \
        if (n_ < NPOS) {                                                          \
          const int pr_ = n_ / 7, pc_ = n_ - pr_ * 7;                             \
          float* orow = og + (size_t)(r0 + pr_) * 112 + (c0 + pc_);               \
          _Pragma("unroll") for (int rg = 0; rg < 16; ++rg) {                     \
            const int o2 = wave * 64 + (MT) * 32 + (rg & 3) + 8 * (rg >> 2) + 4 * g2; \
            orow[(size_t)o2 * 12544] = ACC[rg] + bo_s[o2];                        \
          }                                                                       \
        }                                                                         \
      }
      STORE_OUT(a00, 0, 0)
      STORE_OUT(a01, 0, 1)
      STORE_OUT(a10, 1, 0)
      STORE_OUT(a11, 1, 1)
    }
  }
}

// ---------------- oproj: out[b][oc][row][0..111] = Wo @ attn_out + bo ----------------
__global__ __launch_bounds__(256, 2) void oproj_kernel(
    const __bf16* __restrict__ aoT_g, const __bf16* __restrict__ woP,
    const float* __restrict__ bo_g, float* __restrict__ outg) {
  __shared__ __bf16 aoB[112 * 264];
  __shared__ float bo_s[256];
  const int tid = threadIdx.x;
  const int bid = blockIdx.x;
  const int work = (bid & 7) * 224 + (bid >> 3);
  const int pr = work % 7;
  const int g  = work / 7;
  const int i1 = g & 15, b = g >> 4;
  const int wave = tid >> 6, lane = tid & 63;
  const int c16 = lane & 15, g4 = lane >> 4;

  {
    const int rr = tid >> 5, coff = (tid & 31) * 8;
#pragma unroll
    for (int it = 0; it < 14; ++it) {
      const int gr = it * 8 + rr;
      const int i2 = gr / 7, pc = gr - i2 * 7;
      const size_t src = ((size_t)((b * 256 + i1 * 16 + i2) * 49 + pr * 7 + pc)) * 256 + coff;
      *(bf16x8*)(aoB + gr * 264 + coff) = *(const bf16x8*)(aoT_g + src);
    }
    bo_s[tid] = bo_g[tid];
  }
  __syncthreads();

  const int oc0 = wave * 64;
  // packed wo: tile t = wave*4+mt, frag at ((t*8+kk)*64 + lane)*8
  const __bf16* Ap = woP + ((size_t)wave * 4 * 8) * 512 + lane * 8;
  f32x4 acc[4][7];
#pragma unroll
  for (int mt = 0; mt < 4; ++mt)
#pragma unroll
    for (int nt = 0; nt < 7; ++nt) acc[mt][nt] = f32x4{0.f, 0.f, 0.f, 0.f};
#pragma unroll
  for (int kk = 0; kk < 8; ++kk) {
    bf16x8 Af[4], Bf[7];
#pragma unroll
    for (int mt = 0; mt < 4; ++mt)
      Af[mt] = *(const bf16x8*)(Ap + (size_t)(mt * 8 + kk) * 512);
#pragma unroll
    for (int nt = 0; nt < 7; ++nt)
      Bf[nt] = *(const bf16x8*)(aoB + (nt * 16 + c16) * 264 + kk * 32 + g4 * 8);
    __builtin_amdgcn_s_setprio(1);
#pragma unroll
    for (int mt = 0; mt < 4; ++mt)
#pragma unroll
      for (int nt = 0; nt < 7; ++nt)
        acc[mt][nt] = __builtin_amdgcn_mfma_f32_16x16x32_bf16(Af[mt], Bf[nt], acc[mt][nt], 0, 0, 0);
    __builtin_amdgcn_s_setprio(0);
  }
  float* orow = outg + (size_t)b * 256 * 12544 + (size_t)(i1 * 7 + pr) * 112;
#pragma unroll
  for (int mt = 0; mt < 4; ++mt)
#pragma unroll
    for (int e = 0; e < 4; ++e) {
      const int oc = oc0 + mt * 16 + g4 * 4 + e;
      const float bb = bo_s[oc];
#pragma unroll
      for (int nt = 0; nt < 7; ++nt)
        orow[(size_t)oc * 12544 + nt * 16 + c16] = acc[mt][nt][e] + bb;
    }
}

extern "C" void kernel_launch(void* const* d_in, const int* in_sizes, int n_in,
                              void* d_out, int out_size, void* d_ws, size_t ws_size,
                              hipStream_t stream) {
  const float* x   = (const float*)d_in[0];
  const float* Wq  = (const float*)d_in[1];
  const float* Wkv = (const float*)d_in[2];
  const float* Wo  = (const float*)d_in[3];
  const float* bo  = (const float*)d_in[4];
  const float* pos = (const float*)d_in[5];
  const int*   rel = (const int*)d_in[6];

  float* outg  = (float*)d_out;
  float* attng = outg + (size_t)16 * 256 * 112 * 112;

  // ws layout (bytes, 16B-aligned sections):
  // wqkv 393216 | wo 131072 | bias 9728 | wqkvP 393216 | woP 131072 | aoT | q | k | vT
  __bf16* wqkv  = (__bf16*)d_ws;
  __bf16* wo    = (__bf16*)((char*)d_ws + 393216);
  float*  bias  = (float*)((char*)d_ws + 393216 + 131072);
  __bf16* wqkvP = (__bf16*)((char*)d_ws + 393216 + 131072 + 9728);
  __bf16* woP   = (__bf16*)((char*)d_ws + 393216 + 131072 + 9728 + 393216);
  size_t base = 393216 + 131072 + 9728 + 393216 + 131072;
  base = (base + 255) & ~(size_t)255;

  const size_t ao_bytes = (size_t)4096 * 12544 * 2;
  const size_t qk_bytes = (size_t)4096 * 8 * 3136;   // q or k: [win][h][49][32] bf16
  const size_t vt_bytes = (size_t)4096 * 8 * 4096;   // vT: [win][h][32][64] bf16
  const size_t q_off = base + ao_bytes;
  const size_t k_off = q_off + qk_bytes;
  const size_t v_off = k_off + qk_bytes;
  const size_t full  = v_off + vt_bytes;

  __bf16* aoT_g = (__bf16*)((char*)d_ws + base);
  __bf16* qg    = (__bf16*)((char*)d_ws + q_off);
  __bf16* kg    = (__bf16*)((char*)d_ws + k_off);
  __bf16* vtg   = (__bf16*)((char*)d_ws + v_off);

  hipFuncSetAttribute((const void*)attn_kernel<0>,
                      hipFuncAttributeMaxDynamicSharedMemorySize, LDS_BYTES);
  hipFuncSetAttribute((const void*)attn_kernel<1>,
                      hipFuncAttributeMaxDynamicSharedMemorySize, LDS_BYTES);
  hipFuncSetAttribute((const void*)qkv_kernel,
                      hipFuncAttributeMaxDynamicSharedMemorySize, QKV_LDS);
  hipFuncSetAttribute((const void*)att_kernel,
                      hipFuncAttributeMaxDynamicSharedMemorySize, ATT_LDS);

  prep_kernel<<<dim3(768), dim3(256), 0, stream>>>(Wq, Wkv, Wo, pos, rel, wqkv, wo, bias,
                                                   wqkvP, woP);
  if (ws_size >= full) {
    qkv_kernel<<<dim3(4096), dim3(256), QKV_LDS, stream>>>(x, wqkvP, qg, kg, vtg);
    att_kernel<<<dim3(8192), dim3(256), ATT_LDS, stream>>>(qg, kg, vtg, bias, attng, aoT_g);
    oproj_kernel<<<dim3(1792), dim3(256), 0, stream>>>(aoT_g, woP, bo, outg);
  } else if (ws_size >= base + ao_bytes) {
    attn_kernel<1><<<dim3(4096), dim3(256), LDS_BYTES, stream>>>(
        x, wqkv, wo, bias, bo, outg, attng, aoT_g);
    oproj_kernel<<<dim3(1792), dim3(256), 0, stream>>>(aoT_g, woP, bo, outg);
  } else {
    attn_kernel<0><<<dim3(4096), dim3(256), LDS_BYTES, stream>>>(
        x, wqkv, wo, bias, bo, outg, attng, nullptr);
  }
}

// Round 9
// 426.010 us; speedup vs baseline: 1.4204x; 1.2247x over previous
//
#include <hip/hip_runtime.h>
#include <hip/hip_bf16.h>

typedef __bf16 bf16x8 __attribute__((ext_vector_type(8)));
typedef __bf16 bf16x4 __attribute__((ext_vector_type(4)));
typedef float  f32x4  __attribute__((ext_vector_type(4)));
typedef float  f32x16 __attribute__((ext_vector_type(16)));
typedef float  f32x4a __attribute__((ext_vector_type(4))) __attribute__((aligned(4)));
typedef float  f32x2a __attribute__((ext_vector_type(2))) __attribute__((aligned(4)));

#define NPOS 49
#define NHEADS 8
#define SCALE_F 0.17677669529663687f

// ---- merged-kernel LDS layout (round-5 proven) ----
#define SLICE_B   16896
#define QK_ROW_B  264
#define VS_OFF    8192
#define VS_ROW_B  136
#define XWT_PITCH 264
#define AOT_PITCH 264
#define BIAS_OFF  67584
#define BO_OFF    77188
#define LDS_BYTES 78212

static __device__ __forceinline__ f32x16 zero16() {
  f32x16 z;
#pragma unroll
  for (int i = 0; i < 16; ++i) z[i] = 0.f;
  return z;
}

// prep: bf16 weight copies (legacy fallback) + MFMA-fragment-packed copies
// wqkvP[((s*16+ks)*64 + lane)*8 + e] = W[s*32 + (lane&31)][ks*16 + (lane>>5)*8 + e]
// woP  [((t*8+kk)*64 + lane)*8 + e]  = Wo[t*16 + (lane&15)][kk*32 + (lane>>4)*8 + e]
__global__ void prep_kernel(const float* __restrict__ Wq, const float* __restrict__ Wkv,
                            const float* __restrict__ Wo, const float* __restrict__ pos,
                            const int* __restrict__ rel, __bf16* __restrict__ wqkv,
                            __bf16* __restrict__ wo, float* __restrict__ bias,
                            __bf16* __restrict__ wqkvP, __bf16* __restrict__ woP) {
  const int idx = blockIdx.x * 256 + threadIdx.x;   // 0 .. 768*256-1
  const int row = idx >> 8, col = idx & 255;
  const float wv = (row < 256) ? Wq[idx] : Wkv[idx - 65536];
  wqkv[idx] = (__bf16)wv;
  {
    const int s = row >> 5, l31 = row & 31;
    const int ks = col >> 4, g2 = (col >> 3) & 1, e = col & 7;
    wqkvP[((size_t)((s * 16 + ks) * 64 + g2 * 32 + l31)) * 8 + e] = (__bf16)wv;
  }
  if (idx < 65536) {
    const float w = Wo[idx];
    wo[idx] = (__bf16)w;
    const int t = row >> 4, c16 = row & 15;
    const int kk = col >> 5, g4 = (col >> 3) & 3, e = col & 7;
    woP[((size_t)((t * 8 + kk) * 64 + g4 * 16 + c16)) * 8 + e] = (__bf16)w;
  }
  if (idx < 49 * 49) bias[idx] = pos[rel[idx * 2] * 13 + rel[idx * 2 + 1]];
}

// =====================================================================
// Merged kernel: x-stage -> QKV projection (packed weights) -> attention.
// MODE 1: writes attn + aoT_g (oproj kernel finishes).  MODE 0: monolithic.
// =====================================================================
template <int MODE>
__global__ __launch_bounds__(256, 2) void attn_kernel(
    const float* __restrict__ x, const __bf16* __restrict__ wqkvP,
    const __bf16* __restrict__ wo, const float* __restrict__ bias_g,
    const float* __restrict__ bo_g, float* __restrict__ outg,
    float* __restrict__ attng, __bf16* __restrict__ aoT_g) {
  extern __shared__ char smem[];
  __bf16* xwT = (__bf16*)smem;
  __bf16* aoT = (__bf16*)smem;
  float* bias_s = (float*)(smem + BIAS_OFF);
  float* bo_s   = (float*)(smem + BO_OFF);

  const int tid = threadIdx.x;
  const int bid = blockIdx.x;
  const int work = (bid & 7) * 512 + (bid >> 3);   // XCD swizzle
  const int b  = work >> 8;
  const int i1 = (work >> 4) & 15;
  const int i2 = work & 15;
  const int r0 = i1 * 7, c0 = i2 * 7;
  const int wave = tid >> 6, lane = tid & 63;
  const int l31 = lane & 31, g2 = lane >> 5;
  const int c16 = lane & 15, g4 = lane >> 4;
  char* slice = smem + wave * SLICE_B;

  // ---------- phase 0: stage x window (wide loads, LDS transpose), bias ----------
  {
    // zero-fill pad rows 49..63 (cols 0..255)
    bf16x8 z8;
#pragma unroll
    for (int j = 0; j < 8; ++j) z8[j] = (__bf16)0.f;
    for (int i = tid; i < 480; i += 256) {
      const int row = 49 + (i >> 5);
      const int col = (i & 31) * 8;
      *(bf16x8*)(xwT + row * XWT_PITCH + col) = z8;
    }
    // gather: 1792 (ch, window-row) pairs; 7 per thread; wide loads
    f32x4a b4[7]; f32x2a b2[7]; float b1[7];
    int chv[7], rowv[7];
    const float* xb = x + (size_t)b * 256 * 12544;
#pragma unroll
    for (int k = 0; k < 7; ++k) {
      const int p = k * 256 + tid;
      const int ch = p / 7;
      const int row = p - ch * 7;
      chv[k] = ch; rowv[k] = row;
      const float* xr = xb + (size_t)ch * 12544 + (size_t)(r0 + row) * 112 + c0;
      b4[k] = *(const f32x4a*)xr;
      b2[k] = *(const f32x2a*)(xr + 4);
      b1[k] = xr[6];
    }
#pragma unroll
    for (int k = 0; k < 7; ++k) {
      __bf16* dst = xwT + (rowv[k] * 7) * XWT_PITCH + chv[k];
      dst[0 * XWT_PITCH] = (__bf16)b4[k][0];
      dst[1 * XWT_PITCH] = (__bf16)b4[k][1];
      dst[2 * XWT_PITCH] = (__bf16)b4[k][2];
      dst[3 * XWT_PITCH] = (__bf16)b4[k][3];
      dst[4 * XWT_PITCH] = (__bf16)b2[k][0];
      dst[5 * XWT_PITCH] = (__bf16)b2[k][1];
      dst[6 * XWT_PITCH] = (__bf16)b1[k];
    }
    const float4* bg4 = (const float4*)bias_g;
    for (int i = tid; i < 600; i += 256) ((float4*)bias_s)[i] = bg4[i];
    if (tid == 0) bias_s[2400] = bias_g[2400];
    if constexpr (MODE == 0) bo_s[tid] = bo_g[tid];
  }
  __syncthreads();

  // ---------- GEMM1 B-fragments (xw) -> registers ----------
  bf16x8 Bf0[16], Bf1[16];
  {
    const __bf16* Bp = xwT + l31 * XWT_PITCH + g2 * 8;
#pragma unroll
    for (int ks = 0; ks < 16; ++ks) {
      Bf0[ks] = *(const bf16x8*)(Bp + ks * 16);
      Bf1[ks] = *(const bf16x8*)(Bp + 32 * XWT_PITCH + ks * 16);
    }
  }
  __syncthreads();  // all waves hold B-frags; slices may now be written

  // ---------- GEMM1-v (packed strips 16+2w, 17+2w) ----------
  char* vsb = slice + VS_OFF;
  {
    const __bf16* A0p = wqkvP + (size_t)(16 + 2 * wave) * 8192 + lane * 8;
    const __bf16* A1p = A0p + 8192;
    f32x16 a00 = zero16(), a01 = zero16(), a10 = zero16(), a11 = zero16();
    __builtin_amdgcn_s_setprio(1);
#pragma unroll
    for (int ks = 0; ks < 16; ++ks) {
      bf16x8 A0 = *(const bf16x8*)(A0p + ks * 512);
      bf16x8 A1 = *(const bf16x8*)(A1p + ks * 512);
      a00 = __builtin_amdgcn_mfma_f32_32x32x16_bf16(A0, Bf0[ks], a00, 0, 0, 0);
      a01 = __builtin_amdgcn_mfma_f32_32x32x16_bf16(A0, Bf1[ks], a01, 0, 0, 0);
      a10 = __builtin_amdgcn_mfma_f32_32x32x16_bf16(A1, Bf0[ks], a10, 0, 0, 0);
      a11 = __builtin_amdgcn_mfma_f32_32x32x16_bf16(A1, Bf1[ks], a11, 0, 0, 0);
    }
    __builtin_amdgcn_s_setprio(0);
#pragma unroll
    for (int rg = 0; rg < 16; ++rg) {
      const int dd = (rg & 3) + 8 * (rg >> 2) + 4 * g2;
      *(__bf16*)(vsb + dd * VS_ROW_B + l31 * 2)              = (__bf16)a00[rg];
      *(__bf16*)(vsb + dd * VS_ROW_B + 64 + l31 * 2)         = (__bf16)a01[rg];
      *(__bf16*)(vsb + (32 + dd) * VS_ROW_B + l31 * 2)       = (__bf16)a10[rg];
      *(__bf16*)(vsb + (32 + dd) * VS_ROW_B + 64 + l31 * 2)  = (__bf16)a11[rg];
    }
  }
  bf16x8 vf[2][2][2];
#pragma unroll
  for (int hh = 0; hh < 2; ++hh)
#pragma unroll
    for (int nt = 0; nt < 2; ++nt)
#pragma unroll
      for (int ks = 0; ks < 2; ++ks)
        vf[hh][nt][ks] = *(const bf16x8*)(vsb + (hh * 32 + nt * 16 + c16) * VS_ROW_B + ks * 64 + g4 * 16);
  asm volatile("s_waitcnt lgkmcnt(0)" ::: "memory");
  __builtin_amdgcn_sched_barrier(0x20);  // only VMEM_READ may cross

  // ---------- GEMM1-q (strips 2w,2w+1) and GEMM1-k (strips 8+2w,9+2w) ----------
#pragma unroll
  for (int qk = 0; qk < 2; ++qk) {
    const int koff = qk * 64;  // ELEMENT offset of k region within a row
    const __bf16* A0p = wqkvP + (size_t)(2 * wave + qk * 8) * 8192 + lane * 8;
    const __bf16* A1p = A0p + 8192;
    f32x16 a00 = zero16(), a01 = zero16(), a10 = zero16(), a11 = zero16();
    __builtin_amdgcn_s_setprio(1);
#pragma unroll
    for (int ks = 0; ks < 16; ++ks) {
      bf16x8 A0 = *(const bf16x8*)(A0p + ks * 512);
      bf16x8 A1 = *(const bf16x8*)(A1p + ks * 512);
      a00 = __builtin_amdgcn_mfma_f32_32x32x16_bf16(A0, Bf0[ks], a00, 0, 0, 0);
      a01 = __builtin_amdgcn_mfma_f32_32x32x16_bf16(A0, Bf1[ks], a01, 0, 0, 0);
      a10 = __builtin_amdgcn_mfma_f32_32x32x16_bf16(A1, Bf0[ks], a10, 0, 0, 0);
      a11 = __builtin_amdgcn_mfma_f32_32x32x16_bf16(A1, Bf1[ks], a11, 0, 0, 0);
    }
    __builtin_amdgcn_s_setprio(0);
#define STORE_QK(ACC, P_, NT)                                                  \
    {                                                                          \
      const int n_ = (NT) * 32 + l31;                                          \
      _Pragma("unroll") for (int rb = 0; rb < 4; ++rb) {                       \
        const int ddb = koff + (P_) * 32 + rb * 8 + g2 * 4;                    \
        bf16x4 v4;                                                             \
        v4[0] = (__bf16)ACC[rb * 4 + 0]; v4[1] = (__bf16)ACC[rb * 4 + 1];      \
        v4[2] = (__bf16)ACC[rb * 4 + 2]; v4[3] = (__bf16)ACC[rb * 4 + 3];      \
        *(bf16x4*)(slice + n_ * QK_ROW_B + ddb * 2) = v4;                      \
      }                                                                        \
    }
    STORE_QK(a00, 0, 0)
    STORE_QK(a01, 0, 1)
    STORE_QK(a10, 1, 0)
    STORE_QK(a11, 1, 1)
  }
  bf16x8 qf[2][4], kf[2][4];
#pragma unroll
  for (int hh = 0; hh < 2; ++hh)
#pragma unroll
    for (int t = 0; t < 4; ++t) {
      qf[hh][t] = *(const bf16x8*)(slice + (t * 16 + c16) * QK_ROW_B + hh * 64 + g4 * 16);
      kf[hh][t] = *(const bf16x8*)(slice + (t * 16 + c16) * QK_ROW_B + 128 + hh * 64 + g4 * 16);
    }
  asm volatile("s_waitcnt lgkmcnt(0)" ::: "memory");
  __builtin_amdgcn_sched_barrier(0x20);

  // ---------- attention: both heads interleaved, barrier-free ----------
  f32x4 pacc[2][4][2];
  char* Pb0 = slice;
  char* Pb1 = slice + 8192;
  {
    const f32x4 z4 = {0.f, 0.f, 0.f, 0.f};
    f32x4 dacc[2][4][4];
    __builtin_amdgcn_s_setprio(1);
#pragma unroll
    for (int hh = 0; hh < 2; ++hh)
#pragma unroll
      for (int mt = 0; mt < 4; ++mt)
#pragma unroll
        for (int nt = 0; nt < 4; ++nt)
          dacc[hh][mt][nt] = __builtin_amdgcn_mfma_f32_16x16x32_bf16(qf[hh][mt], kf[hh][nt], z4, 0, 0, 0);
    __builtin_amdgcn_s_setprio(0);

    const int h0 = wave * 2;
    // softmax WITHOUT max-subtraction (scores are O(1); identical to ref math)
#pragma unroll
    for (int mt = 0; mt < 4; ++mt) {
#pragma unroll
      for (int r = 0; r < 4; ++r) {
        const int i = mt * 16 + g4 * 4 + r;
        float p0[4], p1[4], s0 = 0.f, s1 = 0.f;
#pragma unroll
        for (int nt = 0; nt < 4; ++nt) {
          const int j = nt * 16 + c16;
          float v0 = dacc[0][mt][nt][r] * SCALE_F;
          float v1 = dacc[1][mt][nt][r] * SCALE_F;
          if (j < NPOS) {
            if (i < NPOS) { const float bb = bias_s[i * 49 + j]; v0 += bb; v1 += bb; }
          } else {
            v0 = -1e30f; v1 = -1e30f;
          }
          p0[nt] = __expf(v0); s0 += p0[nt];
          p1[nt] = __expf(v1); s1 += p1[nt];
        }
        s0 += __shfl_xor(s0, 1); s1 += __shfl_xor(s1, 1);
        s0 += __shfl_xor(s0, 2); s1 += __shfl_xor(s1, 2);
        s0 += __shfl_xor(s0, 4); s1 += __shfl_xor(s1, 4);
        s0 += __shfl_xor(s0, 8); s1 += __shfl_xor(s1, 8);
        const float inv0 = 1.f / s0, inv1 = 1.f / s1;
        if (i < NPOS) {
          float* ap0 = attng + ((size_t)(work * NHEADS + h0) * 49 + i) * 49;
          float* ap1 = ap0 + 49 * 49;
#pragma unroll
          for (int nt = 0; nt < 4; ++nt) {
            const int j = nt * 16 + c16;
            if (j < NPOS) { ap0[j] = p0[nt] * inv0; ap1[j] = p1[nt] * inv1; }
          }
        }
#pragma unroll
        for (int nt = 0; nt < 4; ++nt) {
          const int j = nt * 16 + c16;
          *(__bf16*)(Pb0 + i * 128 + 16 * ((j >> 3) ^ (i & 7)) + 2 * (j & 7)) = (__bf16)(p0[nt] * inv0);
          *(__bf16*)(Pb1 + i * 128 + 16 * ((j >> 3) ^ (i & 7)) + 2 * (j & 7)) = (__bf16)(p1[nt] * inv1);
        }
      }
    }

    // PV
    __builtin_amdgcn_s_setprio(1);
#pragma unroll
    for (int hh = 0; hh < 2; ++hh) {
      char* Pb = hh ? Pb1 : Pb0;
#pragma unroll
      for (int mt = 0; mt < 4; ++mt) {
        const int i = mt * 16 + c16;
        bf16x8 pa0 = *(const bf16x8*)(Pb + i * 128 + 16 * ((0 + g4) ^ (i & 7)));
        bf16x8 pa1 = *(const bf16x8*)(Pb + i * 128 + 16 * ((4 + g4) ^ (i & 7)));
#pragma unroll
        for (int nt = 0; nt < 2; ++nt) {
          f32x4 acc = {0.f, 0.f, 0.f, 0.f};
          acc = __builtin_amdgcn_mfma_f32_16x16x32_bf16(pa0, vf[hh][nt][0], acc, 0, 0, 0);
          acc = __builtin_amdgcn_mfma_f32_16x16x32_bf16(pa1, vf[hh][nt][1], acc, 0, 0, 0);
          pacc[hh][mt][nt] = acc;
        }
      }
    }
    __builtin_amdgcn_s_setprio(0);
  }

  if constexpr (MODE == 1) {
    // ---------- store attn_out (pre-Wo) -> aoT_g[win][49][256] bf16 ----------
    __bf16* ag = aoT_g + (size_t)work * 12544;
#pragma unroll
    for (int hh = 0; hh < 2; ++hh) {
      const int h = wave * 2 + hh;
#pragma unroll
      for (int mt = 0; mt < 4; ++mt)
#pragma unroll
        for (int e = 0; e < 4; ++e) {
          const int pos = mt * 16 + g4 * 4 + e;
          if (pos < NPOS) {
            ag[pos * 256 + h * 32 + c16]      = (__bf16)pacc[hh][mt][0][e];
            ag[pos * 256 + h * 32 + 16 + c16] = (__bf16)pacc[hh][mt][1][e];
          }
        }
    }
  } else {
    __syncthreads();
#pragma unroll
    for (int hh = 0; hh < 2; ++hh) {
      const int h = wave * 2 + hh;
#pragma unroll
      for (int mt = 0; mt < 4; ++mt)
#pragma unroll
        for (int nt = 0; nt < 2; ++nt)
#pragma unroll
          for (int e = 0; e < 4; ++e) {
            const int i = mt * 16 + g4 * 4 + e;
            const int cc = h * 32 + nt * 16 + c16;
            aoT[i * AOT_PITCH + cc] = (__bf16)pacc[hh][mt][nt][e];
          }
    }
    __syncthreads();
    {
      bf16x8 Cf0[16], Cf1[16];
      const __bf16* Bp = aoT + l31 * AOT_PITCH + g2 * 8;
#pragma unroll
      for (int ks = 0; ks < 16; ++ks) {
        Cf0[ks] = *(const bf16x8*)(Bp + ks * 16);
        Cf1[ks] = *(const bf16x8*)(Bp + 32 * AOT_PITCH + ks * 16);
      }
      const __bf16* Ap0 = wo + (size_t)(wave * 64 + l31) * 256 + g2 * 8;
      const __bf16* Ap1 = Ap0 + 32 * 256;
      f32x16 a00 = zero16(), a01 = zero16(), a10 = zero16(), a11 = zero16();
      __builtin_amdgcn_s_setprio(1);
#pragma unroll
      for (int ks = 0; ks < 16; ++ks) {
        bf16x8 A0 = *(const bf16x8*)(Ap0 + ks * 16);
        bf16x8 A1 = *(const bf16x8*)(Ap1 + ks * 16);
        a00 = __builtin_amdgcn_mfma_f32_32x32x16_bf16(A0, Cf0[ks], a00, 0, 0, 0);
        a01 = __builtin_amdgcn_mfma_f32_32x32x16_bf16(A0, Cf1[ks], a01, 0, 0, 0);
        a10 = __builtin_amdgcn_mfma_f32_32x32x16_bf16(A1, Cf0[ks], a10, 0, 0, 0);
        a11 = __builtin_amdgcn_mfma_f32_32x32x16_bf16(A1, Cf1[ks], a11, 0, 0, 0);
      }
      __builtin_amdgcn_s_setprio(0);
      float* og = outg + (size_t)b * 256 * 12544;
#define STORE_OUT(ACC, MT, NT)                                                    \
      {                                                                           \
        const int n_ = (NT) * 32 + l31;                                           \
        if (n_ < NPOS) {                                                          \
          const int pr_ = n_ / 7, pc_ = n_ - pr_ * 7;                             \
          float* orow = og + (size_t)(r0 + pr_) * 112 + (c0 + pc_);               \
          _Pragma("unroll") for (int rg = 0; rg < 16; ++rg) {                     \
            const int o2 = wave * 64 + (MT) * 32 + (rg & 3) + 8 * (rg >> 2) + 4 * g2; \
            orow[(size_t)o2 * 12544] = ACC[rg] + bo_s[o2];                        \
          }                                                                       \
        }                                                                         \
      }
      STORE_OUT(a00, 0, 0)
      STORE_OUT(a01, 0, 1)
      STORE_OUT(a10, 1, 0)
      STORE_OUT(a11, 1, 1)
    }
  }
}

// ---------------- oproj: out[b][oc][row][0..111] = Wo @ attn_out + bo ----------------
__global__ __launch_bounds__(256, 2) void oproj_kernel(
    const __bf16* __restrict__ aoT_g, const __bf16* __restrict__ woP,
    const float* __restrict__ bo_g, float* __restrict__ outg) {
  __shared__ __bf16 aoB[112 * 264];
  __shared__ float bo_s[256];
  const int tid = threadIdx.x;
  const int bid = blockIdx.x;
  const int work = (bid & 7) * 224 + (bid >> 3);
  const int pr = work % 7;
  const int g  = work / 7;
  const int i1 = g & 15, b = g >> 4;
  const int wave = tid >> 6, lane = tid & 63;
  const int c16 = lane & 15, g4 = lane >> 4;

  {
    const int rr = tid >> 5, coff = (tid & 31) * 8;
#pragma unroll
    for (int it = 0; it < 14; ++it) {
      const int gr = it * 8 + rr;
      const int i2 = gr / 7, pc = gr - i2 * 7;
      const size_t src = ((size_t)((b * 256 + i1 * 16 + i2) * 49 + pr * 7 + pc)) * 256 + coff;
      *(bf16x8*)(aoB + gr * 264 + coff) = *(const bf16x8*)(aoT_g + src);
    }
    bo_s[tid] = bo_g[tid];
  }
  __syncthreads();

  const int oc0 = wave * 64;
  const __bf16* Ap = woP + ((size_t)wave * 4 * 8) * 512 + lane * 8;
  f32x4 acc[4][7];
#pragma unroll
  for (int mt = 0; mt < 4; ++mt)
#pragma unroll
    for (int nt = 0; nt < 7; ++nt) acc[mt][nt] = f32x4{0.f, 0.f, 0.f, 0.f};
#pragma unroll
  for (int kk = 0; kk < 8; ++kk) {
    bf16x8 Af[4], Bf[7];
#pragma unroll
    for (int mt = 0; mt < 4; ++mt)
      Af[mt] = *(const bf16x8*)(Ap + (size_t)(mt * 8 + kk) * 512);
#pragma unroll
    for (int nt = 0; nt < 7; ++nt)
      Bf[nt] = *(const bf16x8*)(aoB + (nt * 16 + c16) * 264 + kk * 32 + g4 * 8);
    __builtin_amdgcn_s_setprio(1);
#pragma unroll
    for (int mt = 0; mt < 4; ++mt)
#pragma unroll
      for (int nt = 0; nt < 7; ++nt)
        acc[mt][nt] = __builtin_amdgcn_mfma_f32_16x16x32_bf16(Af[mt], Bf[nt], acc[mt][nt], 0, 0, 0);
    __builtin_amdgcn_s_setprio(0);
  }
  float* orow = outg + (size_t)b * 256 * 12544 + (size_t)(i1 * 7 + pr) * 112;
#pragma unroll
  for (int mt = 0; mt < 4; ++mt)
#pragma unroll
    for (int e = 0; e < 4; ++e) {
      const int oc = oc0 + mt * 16 + g4 * 4 + e;
      const float bb = bo_s[oc];
#pragma unroll
      for (int nt = 0; nt < 7; ++nt)
        orow[(size_t)oc * 12544 + nt * 16 + c16] = acc[mt][nt][e] + bb;
    }
}

extern "C" void kernel_launch(void* const* d_in, const int* in_sizes, int n_in,
                              void* d_out, int out_size, void* d_ws, size_t ws_size,
                              hipStream_t stream) {
  const float* x   = (const float*)d_in[0];
  const float* Wq  = (const float*)d_in[1];
  const float* Wkv = (const float*)d_in[2];
  const float* Wo  = (const float*)d_in[3];
  const float* bo  = (const float*)d_in[4];
  const float* pos = (const float*)d_in[5];
  const int*   rel = (const int*)d_in[6];

  float* outg  = (float*)d_out;
  float* attng = outg + (size_t)16 * 256 * 112 * 112;

  // ws layout: wqkv 393216 | wo 131072 | bias 9728 | wqkvP 393216 | woP 131072 | aoT
  __bf16* wqkv  = (__bf16*)d_ws;
  __bf16* wo    = (__bf16*)((char*)d_ws + 393216);
  float*  bias  = (float*)((char*)d_ws + 393216 + 131072);
  __bf16* wqkvP = (__bf16*)((char*)d_ws + 393216 + 131072 + 9728);
  __bf16* woP   = (__bf16*)((char*)d_ws + 393216 + 131072 + 9728 + 393216);
  size_t base = 393216 + 131072 + 9728 + 393216 + 131072;
  base = (base + 255) & ~(size_t)255;
  const size_t ao_bytes = (size_t)4096 * 12544 * 2;
  __bf16* aoT_g = (__bf16*)((char*)d_ws + base);
  (void)wqkv;

  hipFuncSetAttribute((const void*)attn_kernel<0>,
                      hipFuncAttributeMaxDynamicSharedMemorySize, LDS_BYTES);
  hipFuncSetAttribute((const void*)attn_kernel<1>,
                      hipFuncAttributeMaxDynamicSharedMemorySize, LDS_BYTES);

  prep_kernel<<<dim3(768), dim3(256), 0, stream>>>(Wq, Wkv, Wo, pos, rel, wqkv, wo, bias,
                                                   wqkvP, woP);
  if (ws_size >= base + ao_bytes) {
    attn_kernel<1><<<dim3(4096), dim3(256), LDS_BYTES, stream>>>(
        x, wqkvP, wo, bias, bo, outg, attng, aoT_g);
    oproj_kernel<<<dim3(1792), dim3(256), 0, stream>>>(aoT_g, woP, bo, outg);
  } else {
    attn_kernel<0><<<dim3(4096), dim3(256), LDS_BYTES, stream>>>(
        x, wqkvP, wo, bias, bo, outg, attng, nullptr);
  }
}